// Round 1
// baseline (1608.481 us; speedup 1.0000x reference)
//
#include <hip/hip_runtime.h>
#include <math.h>

#define BATCH 2
#define CH    192
#define NPTS  8192
#define KNN   9

// phase-1 tiling
#define NT    64     // rows per block
#define MT    128    // cols per m-tile
#define KC    32     // k-chunk staged in LDS
#define TLIST 8      // per-thread per-row candidate list length
#define NCAND 128    // candidates per row (16 tx-bins * TLIST)

// ---------------------------------------------------------------------------
// Kernel A: per-point norms + layouts.
//  x        [B][C][N] f32 (input)
//  pts_cm   [B][C][N] f32 normalized (phase-1 GEMM operand, col-major)
//  x_rm     [B][N][C] f32 raw       (phase-2 exact recompute, row-major)
//  rdnd     [B][N]    f64 1/max(norm,eps)
//  ssd      [B][N]    f64 sum(x^2)
// ---------------------------------------------------------------------------
__global__ __launch_bounds__(256) void knn_normalize(
    const float* __restrict__ x,
    float* __restrict__ pts_cm, float* __restrict__ x_rm,
    double* __restrict__ rdnd, double* __restrict__ ssd)
{
    __shared__ float  tile[CH][NT + 1];
    __shared__ double rdn_sh[NT];

    const int b   = blockIdx.x >> 7;          // 128 blocks per batch
    const int n0  = (blockIdx.x & 127) << 6;  // 64 points per block
    const int tid = threadIdx.x;
    const float* xb = x + (size_t)b * CH * NPTS;

    // stage tile [192][64], coalesced over n
    #pragma unroll
    for (int i = 0; i < (CH * NT) / 256; ++i) {
        int flat = tid + i * 256;
        int c = flat >> 6, j = flat & 63;
        tile[c][j] = xb[(size_t)c * NPTS + n0 + j];
    }
    __syncthreads();

    if (tid < NT) {
        double ss = 0.0;
        #pragma unroll 8
        for (int c = 0; c < CH; ++c) {
            double v = (double)tile[c][tid];
            ss = fma(v, v, ss);
        }
        double dn = sqrt(ss);
        if (dn < 1e-12) dn = 1e-12;
        double rdn = 1.0 / dn;
        rdn_sh[tid] = rdn;
        rdnd[b * NPTS + n0 + tid] = rdn;
        ssd [b * NPTS + n0 + tid] = ss;
    }
    __syncthreads();

    // normalized f32, col-major [B][C][N] (coalesced over n)
    #pragma unroll
    for (int i = 0; i < (CH * NT) / 256; ++i) {
        int flat = tid + i * 256;
        int c = flat >> 6, j = flat & 63;
        pts_cm[(size_t)(b * CH + c) * NPTS + n0 + j] =
            (float)((double)tile[c][j] * rdn_sh[j]);
    }
    // raw f32, row-major [B][N][C] (coalesced over c)
    #pragma unroll
    for (int i = 0; i < (CH * NT) / 256; ++i) {
        int flat = tid + i * 256;
        int j = flat / CH, c = flat - j * CH;
        x_rm[(size_t)(b * NPTS + n0 + j) * CH + c] = tile[c][j];
    }
}

// ---------------------------------------------------------------------------
// Phase 1: f32 inner-product GEMM + per-thread running top-8 candidates.
// Block = 64 rows x all 8192 cols (tiles of 128). 256 threads: ty(16)x tx(16),
// each thread owns 4 rows x 8 cols per tile. Key = -inner (monotone in dist
// since all points are unit-norm to ~1e-7; phase-2 re-ranks exactly anyway).
// ---------------------------------------------------------------------------
__global__ __launch_bounds__(256) void knn_phase1(
    const float* __restrict__ pts_cm,
    float* __restrict__ cand_k, int* __restrict__ cand_i)
{
    __shared__ float A[CH][NT];    // 49152 B
    __shared__ float Bc[KC][MT];   // 16384 B

    const int b   = blockIdx.x >> 7;
    const int n0  = (blockIdx.x & 127) << 6;
    const int tid = threadIdx.x;
    const int ty  = tid >> 4;   // row group: rows 4*ty .. 4*ty+3
    const int tx  = tid & 15;   // col group: cols 8*tx .. 8*tx+7
    const float* P = pts_cm + (size_t)b * CH * NPTS;

    // load full A tile [192][64] as float4 (coalesced)
    #pragma unroll
    for (int i = 0; i < (CH * NT / 4) / 256; ++i) {   // 12
        int f4 = tid + i * 256;
        int c = f4 >> 4, r4 = (f4 & 15) << 2;
        *(float4*)&A[c][r4] = *(const float4*)&P[(size_t)c * NPTS + n0 + r4];
    }

    float kbuf[4][TLIST]; int ibuf[4][TLIST];
    float wmax[4]; int wpos[4];
    #pragma unroll
    for (int i = 0; i < 4; ++i) {
        wmax[i] = INFINITY; wpos[i] = 0;
        #pragma unroll
        for (int t = 0; t < TLIST; ++t) { kbuf[i][t] = INFINITY; ibuf[i][t] = 0; }
    }

    for (int mt = 0; mt < NPTS / MT; ++mt) {
        float acc[4][8];
        #pragma unroll
        for (int i = 0; i < 4; ++i)
            #pragma unroll
            for (int j = 0; j < 8; ++j) acc[i][j] = 0.f;

        for (int kc = 0; kc < CH / KC; ++kc) {
            __syncthreads();
            // stage B chunk [32][128] as float4 (coalesced)
            #pragma unroll
            for (int i = 0; i < 4; ++i) {
                int f4 = tid + i * 256;
                int kk = f4 >> 5, c4 = (f4 & 31) << 2;
                *(float4*)&Bc[kk][c4] =
                    *(const float4*)&P[(size_t)(kc * KC + kk) * NPTS + mt * MT + c4];
            }
            __syncthreads();

            #pragma unroll 8
            for (int kk = 0; kk < KC; ++kk) {
                const float4 av = *(const float4*)&A[kc * KC + kk][ty << 2];
                const float4 b0 = *(const float4*)&Bc[kk][tx << 3];
                const float4 b1 = *(const float4*)&Bc[kk][(tx << 3) + 4];
                float bb[8] = {b0.x, b0.y, b0.z, b0.w, b1.x, b1.y, b1.z, b1.w};
                #pragma unroll
                for (int j = 0; j < 8; ++j) {
                    acc[0][j] = fmaf(av.x, bb[j], acc[0][j]);
                    acc[1][j] = fmaf(av.y, bb[j], acc[1][j]);
                    acc[2][j] = fmaf(av.z, bb[j], acc[2][j]);
                    acc[3][j] = fmaf(av.w, bb[j], acc[3][j]);
                }
            }
        }

        // running top-8 update (all-register, static indexing only)
        const int m0 = (mt << 7) + (tx << 3);
        #pragma unroll
        for (int i = 0; i < 4; ++i) {
            float kmin = -acc[i][0];
            #pragma unroll
            for (int j = 1; j < 8; ++j) kmin = fminf(kmin, -acc[i][j]);
            if (kmin < wmax[i]) {
                #pragma unroll
                for (int j = 0; j < 8; ++j) {
                    float key = -acc[i][j];
                    if (key < wmax[i]) {
                        int id = m0 + j;
                        #pragma unroll
                        for (int t = 0; t < TLIST; ++t)
                            if (t == wpos[i]) { kbuf[i][t] = key; ibuf[i][t] = id; }
                        float nm = kbuf[i][0]; int np_ = 0;
                        #pragma unroll
                        for (int t = 1; t < TLIST; ++t)
                            if (kbuf[i][t] > nm) { nm = kbuf[i][t]; np_ = t; }
                        wmax[i] = nm; wpos[i] = np_;
                    }
                }
            }
        }
    }

    // write candidates: [B*N][128], this thread owns slots tx*8..tx*8+7
    #pragma unroll
    for (int i = 0; i < 4; ++i) {
        size_t row = (size_t)(b * NPTS + n0 + (ty << 2) + i);
        #pragma unroll
        for (int t = 0; t < TLIST; ++t) {
            cand_k[row * NCAND + (tx << 3) + t] = kbuf[i][t];
            cand_i[row * NCAND + (tx << 3) + t] = ibuf[i][t];
        }
    }
}

// ---------------------------------------------------------------------------
// Phase 2: per row, f32-top-16 of 128 candidates, exact f64 re-rank, emit 9.
// Block = 16 rows, 256 threads.
// ---------------------------------------------------------------------------
__global__ __launch_bounds__(256) void knn_phase2(
    const float* __restrict__ x_rm,
    const double* __restrict__ rdnd, const double* __restrict__ ssd,
    const float* __restrict__ cand_k, const int* __restrict__ cand_i,
    int* __restrict__ out)
{
    __shared__ float  ck[16][NCAND + 1];
    __shared__ int    ci[16][NCAND + 1];
    __shared__ double xc[16][CH + 2];     // center rows, f64-normalized
    __shared__ int    sel_i[16][16];
    __shared__ double dk[16][17];

    const int bi  = blockIdx.x;           // 1024 blocks
    const int b   = bi >> 9;
    const int n0  = (bi & 511) << 4;
    const int tid = threadIdx.x;
    const int bN  = b * NPTS;

    #pragma unroll
    for (int i = 0; i < 8; ++i) {
        int flat = tid + i * 256;
        int r = flat >> 7, t = flat & 127;
        size_t o = (size_t)(bN + n0 + r) * NCAND + t;
        ck[r][t] = cand_k[o];
        ci[r][t] = cand_i[o];
    }
    #pragma unroll
    for (int i = 0; i < (16 * CH) / 256; ++i) {   // 12
        int flat = tid + i * 256;
        int r = flat / CH, c = flat - r * CH;
        xc[r][c] = (double)x_rm[(size_t)(bN + n0 + r) * CH + c] * rdnd[bN + n0 + r];
    }
    __syncthreads();

    // per-row serial top-16 of 128 by (key, idx) lex  (threads 0..15)
    if (tid < 16) {
        const int r = tid;
        float sk[16]; int si[16];
        #pragma unroll
        for (int t = 0; t < 16; ++t) { sk[t] = INFINITY; si[t] = 0x7fffffff; }
        for (int t = 0; t < NCAND; ++t) {
            float k = ck[r][t]; int id = ci[r][t];
            bool ins = (k < sk[15]) || (k == sk[15] && id < si[15]);
            if (ins) {
                #pragma unroll
                for (int p = 15; p >= 0; --p) {
                    bool l = (k < sk[p]) || (k == sk[p] && id < si[p]);
                    if (l) {
                        bool up = (p > 0) &&
                                  ((k < sk[p-1]) || (k == sk[p-1] && id < si[p-1]));
                        sk[p] = up ? sk[p-1] : k;
                        si[p] = up ? si[p-1] : id;
                    }
                }
            }
        }
        #pragma unroll
        for (int t = 0; t < 16; ++t) sel_i[r][t] = si[t];
    }
    __syncthreads();

    // exact f64 key for the 16 selected candidates of each row
    {
        const int r = tid >> 4, s = tid & 15;
        const int m = sel_i[r][s];
        const double rdm = rdnd[bN + m];
        const float* base = x_rm + (size_t)(bN + m) * CH;
        double accd = 0.0;
        #pragma unroll 8
        for (int c = 0; c < CH; ++c)
            accd = fma(xc[r][c], (double)base[c] * rdm, accd);
        // key = sq_m - 2*inner   (sq_n is a per-row constant: ranking-safe)
        dk[r][s] = fma(-2.0, accd, ssd[bN + m] * rdm * rdm);
    }
    __syncthreads();

    // per-row: 9 smallest of 16 by (key, idx), write output
    if (tid < 16) {
        const int r = tid;
        const int n = n0 + r;
        unsigned used = 0;
        for (int k = 0; k < KNN; ++k) {
            double bd = INFINITY; int bm = 0x7fffffff; int bp = 0;
            #pragma unroll
            for (int s = 0; s < 16; ++s) {
                if (!((used >> s) & 1u)) {
                    double d = dk[r][s]; int m = sel_i[r][s];
                    if (d < bd || (d == bd && m < bm)) { bd = d; bm = m; bp = s; }
                }
            }
            used |= (1u << bp);
            out[(size_t)(bN + n) * KNN + k] = bm;
            out[(size_t)BATCH * NPTS * KNN + (size_t)(bN + n) * KNN + k] = n;
        }
    }
}

// ---------------------------------------------------------------------------
extern "C" void kernel_launch(void* const* d_in, const int* in_sizes, int n_in,
                              void* d_out, int out_size, void* d_ws, size_t ws_size,
                              hipStream_t stream)
{
    const float* x = (const float*)d_in[0];
    int* out = (int*)d_out;

    char* ws = (char*)d_ws;
    const size_t sz_pts  = (size_t)BATCH * CH * NPTS * sizeof(float);   // 12.6 MB
    const size_t sz_xrm  = sz_pts;                                      // 12.6 MB
    const size_t sz_rdn  = (size_t)BATCH * NPTS * sizeof(double);       // 128 KB
    const size_t sz_ss   = sz_rdn;
    const size_t sz_ck   = (size_t)BATCH * NPTS * NCAND * sizeof(float);// 8.4 MB
    float*  pts_cm = (float*) (ws);
    float*  x_rm   = (float*) (ws + sz_pts);
    double* rdnd   = (double*)(ws + sz_pts + sz_xrm);
    double* ssd    = (double*)(ws + sz_pts + sz_xrm + sz_rdn);
    float*  cand_k = (float*) (ws + sz_pts + sz_xrm + sz_rdn + sz_ss);
    int*    cand_i = (int*)   (ws + sz_pts + sz_xrm + sz_rdn + sz_ss + sz_ck);

    knn_normalize<<<BATCH * (NPTS / NT), 256, 0, stream>>>(x, pts_cm, x_rm, rdnd, ssd);
    knn_phase1  <<<BATCH * (NPTS / NT), 256, 0, stream>>>(pts_cm, cand_k, cand_i);
    knn_phase2  <<<BATCH * (NPTS / 16), 256, 0, stream>>>(x_rm, rdnd, ssd, cand_k, cand_i, out);
}

// Round 2
// 1244.573 us; speedup vs baseline: 1.2924x; 1.2924x over previous
//
#include <hip/hip_runtime.h>
#include <math.h>

#define BATCH 2
#define CH    192
#define NPTS  8192
#define KNN   9

#define NT    64       // rows per normalize block
#define TLIST 8        // per-(lane,slot) candidate list length
#define NCAND 128      // candidates per row (16 bins * TLIST)
#define NTILE 512      // NPTS/16 row/col tiles per batch
#define KSTEP 6        // 192 / 32

typedef __attribute__((ext_vector_type(8))) short  bf16x8;
typedef __attribute__((ext_vector_type(8))) unsigned short u16x8;
typedef __attribute__((ext_vector_type(4))) float  f32x4;

static __device__ __forceinline__ unsigned short f2bf(float f) {
    unsigned u = __float_as_uint(f);
    u += 0x7fffu + ((u >> 16) & 1u);          // round-to-nearest-even
    return (unsigned short)(u >> 16);
}
static __device__ __forceinline__ float bf2f(unsigned short h) {
    return __uint_as_float(((unsigned)h) << 16);
}

// ---------------------------------------------------------------------------
// Kernel A: norms + layouts.
//  x     [B][C][N] f32 (input)
//  pk    [B][tile(512)][ks(6)][half(2)][lane(64)*8] bf16  — MFMA frag layout
//        element: row = tile*16 + (lane&15), k = ks*32 + (lane>>4)*8 + e
//  x_rm  [B][N][C] f32 raw  (phase-2 exact recompute)
//  rdnd  [B][N] f64 1/max(norm,eps);  ssd [B][N] f64 sum(x^2)
// ---------------------------------------------------------------------------
__global__ __launch_bounds__(256) void knn_normalize(
    const float* __restrict__ x,
    unsigned short* __restrict__ pk, float* __restrict__ x_rm,
    double* __restrict__ rdnd, double* __restrict__ ssd)
{
    __shared__ float  tile[CH][NT + 1];
    __shared__ double rdn_sh[NT];

    const int b   = blockIdx.x >> 7;          // 128 blocks per batch
    const int rb  = blockIdx.x & 127;
    const int n0  = rb << 6;                  // 64 points per block
    const int tid = threadIdx.x;
    const float* xb = x + (size_t)b * CH * NPTS;

    #pragma unroll
    for (int i = 0; i < (CH * NT) / 256; ++i) {
        int flat = tid + i * 256;
        int c = flat >> 6, j = flat & 63;
        tile[c][j] = xb[(size_t)c * NPTS + n0 + j];
    }
    __syncthreads();

    if (tid < NT) {
        double ss = 0.0;
        #pragma unroll 8
        for (int c = 0; c < CH; ++c) {
            double v = (double)tile[c][tid];
            ss = fma(v, v, ss);
        }
        double dn = sqrt(ss);
        if (dn < 1e-12) dn = 1e-12;
        double rdn = 1.0 / dn;
        rdn_sh[tid] = rdn;
        rdnd[b * NPTS + n0 + tid] = rdn;
        ssd [b * NPTS + n0 + tid] = ss;
    }
    __syncthreads();

    // packed MFMA-frag bf16 hi/lo (4 row-tiles * 6 ksteps = 24 frags/block)
    #pragma unroll
    for (int i = 0; i < 6; ++i) {
        int pid  = tid + i * 256;             // 0..1535 = 24 frags * 64 lanes
        int frag = pid >> 6;
        int lane = pid & 63;
        int tl   = frag / KSTEP;              // 0..3
        int ks   = frag - tl * KSTEP;
        int rl   = (tl << 4) + (lane & 15);   // local row 0..63
        int kb   = (ks << 5) + ((lane >> 4) << 3);
        double rdn = rdn_sh[rl];
        u16x8 hv, lv;
        #pragma unroll
        for (int e = 0; e < 8; ++e) {
            float v = (float)((double)tile[kb + e][rl] * rdn);
            unsigned short h = f2bf(v);
            hv[e] = h;
            lv[e] = f2bf(v - bf2f(h));
        }
        size_t base = ((size_t)((b * NTILE + (rb << 2) + tl) * KSTEP + ks)) * 1024
                      + ((size_t)lane << 3);
        *(u16x8*)(pk + base)       = hv;
        *(u16x8*)(pk + base + 512) = lv;
    }

    // raw f32, row-major [B][N][C]
    #pragma unroll
    for (int i = 0; i < (CH * NT) / 256; ++i) {
        int flat = tid + i * 256;
        int j = flat / CH, c = flat - j * CH;
        x_rm[(size_t)(b * NPTS + n0 + j) * CH + c] = tile[c][j];
    }
}

// ---------------------------------------------------------------------------
// Phase 1: bf16x3 MFMA inner products + per-lane running top-8 per row-slot.
// Block = 4 waves; wave w owns row tile rb*4+w (16 rows), sweeps all 512 col
// tiles (4 per iteration). A-frags in registers, B-frags streamed from global
// (L1/L2 resident). C/D: col=lane&15, row=(lane>>4)*4+reg.
// Bin for a row's candidates = lane&15 = col mod 16  (16 bins * 8 = 128).
// ---------------------------------------------------------------------------
__global__ __launch_bounds__(256, 1) void knn_phase1(
    const unsigned short* __restrict__ pk,
    float* __restrict__ cand_k, int* __restrict__ cand_i)
{
    const int b    = blockIdx.x >> 7;
    const int rb   = blockIdx.x & 127;
    const int wave = threadIdx.x >> 6;
    const int lane = threadIdx.x & 63;
    const int rt   = (rb << 2) + wave;                 // row tile 0..511
    const unsigned short* pkb = pk + (size_t)b * (NTILE * KSTEP * 1024);

    bf16x8 a_hi[KSTEP], a_lo[KSTEP];
    #pragma unroll
    for (int ks = 0; ks < KSTEP; ++ks) {
        const unsigned short* p = pkb + ((size_t)(rt * KSTEP + ks)) * 1024 + (lane << 3);
        a_hi[ks] = *(const bf16x8*)p;
        a_lo[ks] = *(const bf16x8*)(p + 512);
    }

    float kbuf[4][TLIST]; int ibuf[4][TLIST];
    float wmax[4]; int wpos[4];
    #pragma unroll
    for (int s = 0; s < 4; ++s) {
        wmax[s] = INFINITY; wpos[s] = 0;
        #pragma unroll
        for (int t = 0; t < TLIST; ++t) { kbuf[s][t] = INFINITY; ibuf[s][t] = 0; }
    }

    for (int ct = 0; ct < NTILE; ct += 4) {
        f32x4 acc[4];
        #pragma unroll
        for (int j = 0; j < 4; ++j) acc[j] = (f32x4){0.f, 0.f, 0.f, 0.f};

        #pragma unroll
        for (int ks = 0; ks < KSTEP; ++ks) {
            bf16x8 bh[4], bl[4];
            #pragma unroll
            for (int j = 0; j < 4; ++j) {
                const unsigned short* p =
                    pkb + ((size_t)((ct + j) * KSTEP + ks)) * 1024 + (lane << 3);
                bh[j] = *(const bf16x8*)p;
                bl[j] = *(const bf16x8*)(p + 512);
            }
            #pragma unroll
            for (int j = 0; j < 4; ++j)
                acc[j] = __builtin_amdgcn_mfma_f32_16x16x32_bf16(a_hi[ks], bh[j], acc[j], 0, 0, 0);
            #pragma unroll
            for (int j = 0; j < 4; ++j)
                acc[j] = __builtin_amdgcn_mfma_f32_16x16x32_bf16(a_hi[ks], bl[j], acc[j], 0, 0, 0);
            #pragma unroll
            for (int j = 0; j < 4; ++j)
                acc[j] = __builtin_amdgcn_mfma_f32_16x16x32_bf16(a_lo[ks], bh[j], acc[j], 0, 0, 0);
        }

        // running top-8 per (lane, row-slot)
        #pragma unroll
        for (int j = 0; j < 4; ++j) {
            const int col = ((ct + j) << 4) + (lane & 15);
            #pragma unroll
            for (int s = 0; s < 4; ++s) {
                float key = -acc[j][s];
                if (key < wmax[s]) {
                    #pragma unroll
                    for (int t = 0; t < TLIST; ++t)
                        if (t == wpos[s]) { kbuf[s][t] = key; ibuf[s][t] = col; }
                    float nm = kbuf[s][0]; int np_ = 0;
                    #pragma unroll
                    for (int t = 1; t < TLIST; ++t)
                        if (kbuf[s][t] > nm) { nm = kbuf[s][t]; np_ = t; }
                    wmax[s] = nm; wpos[s] = np_;
                }
            }
        }
    }

    // write candidates: row-major [B*N][128], bin = lane&15
    const int bin = lane & 15;
    #pragma unroll
    for (int s = 0; s < 4; ++s) {
        int row = (rt << 4) + ((lane >> 4) << 2) + s;
        size_t base = ((size_t)(b * NPTS + row)) * NCAND + (bin << 3);
        #pragma unroll
        for (int t = 0; t < TLIST; ++t) {
            cand_k[base + t] = kbuf[s][t];
            cand_i[base + t] = ibuf[s][t];
        }
    }
}

// ---------------------------------------------------------------------------
// Phase 2: per row, f32-top-16 of 128 candidates, exact f64 re-rank, emit 9.
// (unchanged from the passing round)
// ---------------------------------------------------------------------------
__global__ __launch_bounds__(256) void knn_phase2(
    const float* __restrict__ x_rm,
    const double* __restrict__ rdnd, const double* __restrict__ ssd,
    const float* __restrict__ cand_k, const int* __restrict__ cand_i,
    int* __restrict__ out)
{
    __shared__ float  ck[16][NCAND + 1];
    __shared__ int    ci[16][NCAND + 1];
    __shared__ double xc[16][CH + 2];
    __shared__ int    sel_i[16][16];
    __shared__ double dk[16][17];

    const int bi  = blockIdx.x;
    const int b   = bi >> 9;
    const int n0  = (bi & 511) << 4;
    const int tid = threadIdx.x;
    const int bN  = b * NPTS;

    #pragma unroll
    for (int i = 0; i < 8; ++i) {
        int flat = tid + i * 256;
        int r = flat >> 7, t = flat & 127;
        size_t o = (size_t)(bN + n0 + r) * NCAND + t;
        ck[r][t] = cand_k[o];
        ci[r][t] = cand_i[o];
    }
    #pragma unroll
    for (int i = 0; i < (16 * CH) / 256; ++i) {
        int flat = tid + i * 256;
        int r = flat / CH, c = flat - r * CH;
        xc[r][c] = (double)x_rm[(size_t)(bN + n0 + r) * CH + c] * rdnd[bN + n0 + r];
    }
    __syncthreads();

    if (tid < 16) {
        const int r = tid;
        float sk[16]; int si[16];
        #pragma unroll
        for (int t = 0; t < 16; ++t) { sk[t] = INFINITY; si[t] = 0x7fffffff; }
        for (int t = 0; t < NCAND; ++t) {
            float k = ck[r][t]; int id = ci[r][t];
            bool ins = (k < sk[15]) || (k == sk[15] && id < si[15]);
            if (ins) {
                #pragma unroll
                for (int p = 15; p >= 0; --p) {
                    bool l = (k < sk[p]) || (k == sk[p] && id < si[p]);
                    if (l) {
                        bool up = (p > 0) &&
                                  ((k < sk[p-1]) || (k == sk[p-1] && id < si[p-1]));
                        sk[p] = up ? sk[p-1] : k;
                        si[p] = up ? si[p-1] : id;
                    }
                }
            }
        }
        #pragma unroll
        for (int t = 0; t < 16; ++t) sel_i[r][t] = si[t];
    }
    __syncthreads();

    {
        const int r = tid >> 4, s = tid & 15;
        const int m = sel_i[r][s];
        const double rdm = rdnd[bN + m];
        const float* base = x_rm + (size_t)(bN + m) * CH;
        double accd = 0.0;
        #pragma unroll 8
        for (int c = 0; c < CH; ++c)
            accd = fma(xc[r][c], (double)base[c] * rdm, accd);
        dk[r][s] = fma(-2.0, accd, ssd[bN + m] * rdm * rdm);
    }
    __syncthreads();

    if (tid < 16) {
        const int r = tid;
        const int n = n0 + r;
        unsigned used = 0;
        for (int k = 0; k < KNN; ++k) {
            double bd = INFINITY; int bm = 0x7fffffff; int bp = 0;
            #pragma unroll
            for (int s = 0; s < 16; ++s) {
                if (!((used >> s) & 1u)) {
                    double d = dk[r][s]; int m = sel_i[r][s];
                    if (d < bd || (d == bd && m < bm)) { bd = d; bm = m; bp = s; }
                }
            }
            used |= (1u << bp);
            out[(size_t)(bN + n) * KNN + k] = bm;
            out[(size_t)BATCH * NPTS * KNN + (size_t)(bN + n) * KNN + k] = n;
        }
    }
}

// ---------------------------------------------------------------------------
extern "C" void kernel_launch(void* const* d_in, const int* in_sizes, int n_in,
                              void* d_out, int out_size, void* d_ws, size_t ws_size,
                              hipStream_t stream)
{
    const float* x = (const float*)d_in[0];
    int* out = (int*)d_out;

    char* ws = (char*)d_ws;
    const size_t sz_pk  = (size_t)BATCH * NTILE * KSTEP * 1024 * sizeof(unsigned short); // 12.58 MB
    const size_t sz_xrm = (size_t)BATCH * NPTS * CH * sizeof(float);                     // 12.58 MB
    const size_t sz_rdn = (size_t)BATCH * NPTS * sizeof(double);
    const size_t sz_ss  = sz_rdn;
    const size_t sz_ck  = (size_t)BATCH * NPTS * NCAND * sizeof(float);                  // 8.4 MB

    unsigned short* pk   = (unsigned short*)(ws);
    float*  x_rm   = (float*) (ws + sz_pk);
    double* rdnd   = (double*)(ws + sz_pk + sz_xrm);
    double* ssd    = (double*)(ws + sz_pk + sz_xrm + sz_rdn);
    float*  cand_k = (float*) (ws + sz_pk + sz_xrm + sz_rdn + sz_ss);
    int*    cand_i = (int*)   (ws + sz_pk + sz_xrm + sz_rdn + sz_ss + sz_ck);

    knn_normalize<<<BATCH * (NPTS / NT), 256, 0, stream>>>(x, pk, x_rm, rdnd, ssd);
    knn_phase1  <<<BATCH * (NPTS / NT), 256, 0, stream>>>(pk, cand_k, cand_i);
    knn_phase2  <<<BATCH * (NPTS / 16), 256, 0, stream>>>(x_rm, rdnd, ssd, cand_k, cand_i, out);
}

// Round 3
// 901.983 us; speedup vs baseline: 1.7833x; 1.3798x over previous
//
#include <hip/hip_runtime.h>
#include <math.h>

#define BATCH 2
#define CH    192
#define NPTS  8192
#define KNN   9

#define NT     64      // rows per normalize block
#define TLIST  8       // per-bucket candidate list length
#define NTILE  512     // 16-wide row/col tiles per batch
#define KSTEP  6       // 192 / 32
#define CSPLIT 2       // column splits (phase 1)
#define CT     2       // col tiles staged per iteration
#define NITER  ((NTILE / CSPLIT) / CT)   // 128
#define NCAND2 256     // candidates per row total (2 splits * 16 bins * 8)

typedef __attribute__((ext_vector_type(8))) short  bf16x8;
typedef __attribute__((ext_vector_type(8))) unsigned short u16x8;
typedef __attribute__((ext_vector_type(4))) float  f32x4;

static __device__ __forceinline__ unsigned short f2bf(float f) {
    unsigned u = __float_as_uint(f);
    u += 0x7fffu + ((u >> 16) & 1u);          // round-to-nearest-even
    return (unsigned short)(u >> 16);
}
static __device__ __forceinline__ float bf2f(unsigned short h) {
    return __uint_as_float(((unsigned)h) << 16);
}

// ---------------------------------------------------------------------------
// Kernel A: norms + layouts (unchanged from passing round).
//  pk    [B][tile(512)][ks(6)][half(2)][lane(64)*8] bf16  — MFMA frag layout
//        element: row = tile*16 + (lane&15), k = ks*32 + (lane>>4)*8 + e
// ---------------------------------------------------------------------------
__global__ __launch_bounds__(256) void knn_normalize(
    const float* __restrict__ x,
    unsigned short* __restrict__ pk, float* __restrict__ x_rm,
    double* __restrict__ rdnd, double* __restrict__ ssd)
{
    __shared__ float  tile[CH][NT + 1];
    __shared__ double rdn_sh[NT];

    const int b   = blockIdx.x >> 7;
    const int rb  = blockIdx.x & 127;
    const int n0  = rb << 6;
    const int tid = threadIdx.x;
    const float* xb = x + (size_t)b * CH * NPTS;

    #pragma unroll
    for (int i = 0; i < (CH * NT) / 256; ++i) {
        int flat = tid + i * 256;
        int c = flat >> 6, j = flat & 63;
        tile[c][j] = xb[(size_t)c * NPTS + n0 + j];
    }
    __syncthreads();

    if (tid < NT) {
        double ss = 0.0;
        #pragma unroll 8
        for (int c = 0; c < CH; ++c) {
            double v = (double)tile[c][tid];
            ss = fma(v, v, ss);
        }
        double dn = sqrt(ss);
        if (dn < 1e-12) dn = 1e-12;
        double rdn = 1.0 / dn;
        rdn_sh[tid] = rdn;
        rdnd[b * NPTS + n0 + tid] = rdn;
        ssd [b * NPTS + n0 + tid] = ss;
    }
    __syncthreads();

    #pragma unroll
    for (int i = 0; i < 6; ++i) {
        int pid  = tid + i * 256;
        int frag = pid >> 6;
        int lane = pid & 63;
        int tl   = frag / KSTEP;
        int ks   = frag - tl * KSTEP;
        int rl   = (tl << 4) + (lane & 15);
        int kb   = (ks << 5) + ((lane >> 4) << 3);
        double rdn = rdn_sh[rl];
        u16x8 hv, lv;
        #pragma unroll
        for (int e = 0; e < 8; ++e) {
            float v = (float)((double)tile[kb + e][rl] * rdn);
            unsigned short h = f2bf(v);
            hv[e] = h;
            lv[e] = f2bf(v - bf2f(h));
        }
        size_t base = ((size_t)((b * NTILE + (rb << 2) + tl) * KSTEP + ks)) * 1024
                      + ((size_t)lane << 3);
        *(u16x8*)(pk + base)       = hv;
        *(u16x8*)(pk + base + 512) = lv;
    }

    #pragma unroll
    for (int i = 0; i < (CH * NT) / 256; ++i) {
        int flat = tid + i * 256;
        int j = flat / CH, c = flat - j * CH;
        x_rm[(size_t)(b * NPTS + n0 + j) * CH + c] = tile[c][j];
    }
}

// ---------------------------------------------------------------------------
// Phase 1: LDS-staged double-buffered bf16x3 MFMA + register top-8 buckets.
// Grid 256 = B(2) x rowblock(64, 128 rows) x colsplit(2). 4 waves; wave w
// owns row tiles rb*8+2w, rb*8+2w+1 (A-frags in registers). Per iter CT=2
// col tiles (24 KiB) staged via global_load_lds, consumed by all 4 waves.
// Bucket = (cs, col&15), depth 8 -> 256 candidates/row.
// ---------------------------------------------------------------------------
__global__ __launch_bounds__(256, 1) void knn_phase1(
    const unsigned short* __restrict__ pk,
    float* __restrict__ cand_k, unsigned short* __restrict__ cand_i)
{
    __shared__ unsigned short ldsB[2][CT * KSTEP * 1024];   // 2 x 24576 B

    const int bid  = blockIdx.x;
    const int b    = bid >> 7;
    const int r7   = bid & 127;
    const int rb   = r7 >> 1;         // row block (128 rows)
    const int cs   = r7 & 1;          // column split
    const int tid  = threadIdx.x;
    const int wave = tid >> 6;
    const int lane = tid & 63;
    const unsigned short* pkb = pk + (size_t)b * (NTILE * KSTEP * 1024);
    const int ct0 = cs * (NTILE / CSPLIT);

    // A fragments for 2 row tiles
    bf16x8 a_hi[2][KSTEP], a_lo[2][KSTEP];
    #pragma unroll
    for (int ri = 0; ri < 2; ++ri) {
        const int rt = rb * 8 + wave * 2 + ri;
        #pragma unroll
        for (int ks = 0; ks < KSTEP; ++ks) {
            const unsigned short* p = pkb + ((size_t)(rt * KSTEP + ks)) * 1024 + (lane << 3);
            a_hi[ri][ks] = *(const bf16x8*)p;
            a_lo[ri][ks] = *(const bf16x8*)(p + 512);
        }
    }

    float kbuf[8][TLIST]; int ibuf[8][TLIST];
    float wmax[8]; int wpos[8];
    #pragma unroll
    for (int s = 0; s < 8; ++s) {
        wmax[s] = INFINITY; wpos[s] = 0;
        #pragma unroll
        for (int t = 0; t < TLIST; ++t) { kbuf[s][t] = INFINITY; ibuf[s][t] = 0; }
    }

    // prologue stage of buffer 0
    {
        const char* g = (const char*)(pkb + (size_t)ct0 * (KSTEP * 1024));
        #pragma unroll
        for (int k = 0; k < 6; ++k) {
            int off = (k * 256 + tid) * 16;
            __builtin_amdgcn_global_load_lds(
                (const __attribute__((address_space(1))) unsigned int*)(g + off),
                (__attribute__((address_space(3))) unsigned int*)((char*)&ldsB[0][0] + off),
                16, 0, 0);
        }
    }
    __syncthreads();

    for (int it = 0; it < NITER; ++it) {
        const int cur = it & 1;
        if (it + 1 < NITER) {
            const char* g = (const char*)(pkb + (size_t)(ct0 + (it + 1) * CT) * (KSTEP * 1024));
            #pragma unroll
            for (int k = 0; k < 6; ++k) {
                int off = (k * 256 + tid) * 16;
                __builtin_amdgcn_global_load_lds(
                    (const __attribute__((address_space(1))) unsigned int*)(g + off),
                    (__attribute__((address_space(3))) unsigned int*)((char*)&ldsB[cur ^ 1][0] + off),
                    16, 0, 0);
            }
        }

        f32x4 acc[2][CT];
        #pragma unroll
        for (int ri = 0; ri < 2; ++ri)
            #pragma unroll
            for (int j = 0; j < CT; ++j) acc[ri][j] = (f32x4){0.f, 0.f, 0.f, 0.f};

        #pragma unroll
        for (int ks = 0; ks < KSTEP; ++ks) {
            bf16x8 bh[CT], bl[CT];
            #pragma unroll
            for (int j = 0; j < CT; ++j) {
                const unsigned short* p = &ldsB[cur][(j * KSTEP + ks) * 1024 + (lane << 3)];
                bh[j] = *(const bf16x8*)p;
                bl[j] = *(const bf16x8*)(p + 512);
            }
            #pragma unroll
            for (int ri = 0; ri < 2; ++ri)
                #pragma unroll
                for (int j = 0; j < CT; ++j) {
                    acc[ri][j] = __builtin_amdgcn_mfma_f32_16x16x32_bf16(a_hi[ri][ks], bh[j], acc[ri][j], 0, 0, 0);
                    acc[ri][j] = __builtin_amdgcn_mfma_f32_16x16x32_bf16(a_hi[ri][ks], bl[j], acc[ri][j], 0, 0, 0);
                    acc[ri][j] = __builtin_amdgcn_mfma_f32_16x16x32_bf16(a_lo[ri][ks], bh[j], acc[ri][j], 0, 0, 0);
                }
        }

        // running top-8 per (row-slot, bucket)
        const int colbase = ((ct0 + it * CT) << 4) + (lane & 15);
        #pragma unroll
        for (int ri = 0; ri < 2; ++ri)
            #pragma unroll
            for (int j = 0; j < CT; ++j) {
                const int col = colbase + (j << 4);
                #pragma unroll
                for (int s = 0; s < 4; ++s) {
                    const int sl = ri * 4 + s;
                    float key = -acc[ri][j][s];
                    if (key < wmax[sl]) {
                        #pragma unroll
                        for (int t = 0; t < TLIST; ++t)
                            if (t == wpos[sl]) { kbuf[sl][t] = key; ibuf[sl][t] = col; }
                        float nm = kbuf[sl][0]; int np_ = 0;
                        #pragma unroll
                        for (int t = 1; t < TLIST; ++t)
                            if (kbuf[sl][t] > nm) { nm = kbuf[sl][t]; np_ = t; }
                        wmax[sl] = nm; wpos[sl] = np_;
                    }
                }
            }
        __syncthreads();
    }

    // write candidates: [B*N][256], slot = cs*128 + bin*8 + t
    #pragma unroll
    for (int ri = 0; ri < 2; ++ri) {
        const int rt = rb * 8 + wave * 2 + ri;
        #pragma unroll
        for (int s = 0; s < 4; ++s) {
            int row = (rt << 4) + ((lane >> 4) << 2) + s;
            size_t base = ((size_t)(b * NPTS + row) << 8) + (cs << 7) + ((lane & 15) << 3);
            #pragma unroll
            for (int t = 0; t < TLIST; ++t) {
                cand_k[base + t] = kbuf[ri * 4 + s][t];
                cand_i[base + t] = (unsigned short)ibuf[ri * 4 + s][t];
            }
        }
    }
}

// ---------------------------------------------------------------------------
// Phase 2: f32-top-16 of 256 candidates, exact f64 re-rank (wave-per-
// candidate, coalesced), emit 9. Block = 16 rows, 256 threads.
// ---------------------------------------------------------------------------
__global__ __launch_bounds__(256) void knn_phase2(
    const float* __restrict__ x_rm,
    const double* __restrict__ rdnd, const double* __restrict__ ssd,
    const float* __restrict__ cand_k, const unsigned short* __restrict__ cand_i,
    int* __restrict__ out)
{
    __shared__ float  ck[16][NCAND2 + 1];
    __shared__ unsigned short ci[16][NCAND2 + 2];
    __shared__ double xc[16][CH];
    __shared__ int    sel_i[16][17];
    __shared__ double dk[16][17];

    const int bi  = blockIdx.x;
    const int b   = bi >> 9;
    const int n0  = (bi & 511) << 4;
    const int tid = threadIdx.x;
    const int bN  = b * NPTS;

    #pragma unroll
    for (int i = 0; i < 16; ++i) {
        int flat = tid + i * 256;
        int r = flat >> 8, t = flat & 255;
        size_t o = (size_t)(bN + n0 + r) * NCAND2 + t;
        ck[r][t] = cand_k[o];
        ci[r][t] = cand_i[o];
    }
    #pragma unroll
    for (int i = 0; i < (16 * CH) / 256; ++i) {
        int flat = tid + i * 256;
        int r = flat / CH, c = flat - r * CH;
        xc[r][c] = (double)x_rm[(size_t)(bN + n0 + r) * CH + c] * rdnd[bN + n0 + r];
    }
    __syncthreads();

    // (b) serial top-16 of 256 by (key, idx) lex — threads 0..15
    if (tid < 16) {
        const int r = tid;
        float sk[16]; int si[16];
        #pragma unroll
        for (int t = 0; t < 16; ++t) { sk[t] = INFINITY; si[t] = 0x7fffffff; }
        for (int t = 0; t < NCAND2; ++t) {
            float k = ck[r][t]; int id = (int)ci[r][t];
            bool ins = (k < sk[15]) || (k == sk[15] && id < si[15]);
            if (ins) {
                #pragma unroll
                for (int p = 15; p >= 0; --p) {
                    bool l = (k < sk[p]) || (k == sk[p] && id < si[p]);
                    if (l) {
                        bool up = (p > 0) &&
                                  ((k < sk[p-1]) || (k == sk[p-1] && id < si[p-1]));
                        sk[p] = up ? sk[p-1] : k;
                        si[p] = up ? si[p-1] : id;
                    }
                }
            }
        }
        #pragma unroll
        for (int t = 0; t < 16; ++t) sel_i[r][t] = si[t];
    }
    __syncthreads();

    // (c) exact f64 keys, one wave per candidate (coalesced loads + shfl reduce)
    {
        const int wave = tid >> 6, lane = tid & 63;
        for (int i = 0; i < 64; ++i) {
            const int q = (wave << 6) + i;
            const int r = q >> 4, s = q & 15;
            const int m = sel_i[r][s];
            const double rdm = rdnd[bN + m];
            const float* xr = x_rm + (size_t)(bN + m) * CH;
            double p = 0.0;
            #pragma unroll
            for (int u = 0; u < 3; ++u) {
                int c = lane + (u << 6);
                p = fma(xc[r][c], (double)xr[c] * rdm, p);
            }
            #pragma unroll
            for (int off = 32; off; off >>= 1) p += __shfl_xor(p, off, 64);
            if (lane == 0) dk[r][s] = fma(-2.0, p, ssd[bN + m] * rdm * rdm);
        }
    }
    __syncthreads();

    // (d) per-row: 9 smallest of 16 by (key, idx)
    if (tid < 16) {
        const int r = tid;
        const int n = n0 + r;
        unsigned used = 0;
        for (int k = 0; k < KNN; ++k) {
            double bd = INFINITY; int bm = 0x7fffffff; int bp = 0;
            #pragma unroll
            for (int s = 0; s < 16; ++s) {
                if (!((used >> s) & 1u)) {
                    double d = dk[r][s]; int m = sel_i[r][s];
                    if (d < bd || (d == bd && m < bm)) { bd = d; bm = m; bp = s; }
                }
            }
            used |= (1u << bp);
            out[(size_t)(bN + n) * KNN + k] = bm;
            out[(size_t)BATCH * NPTS * KNN + (size_t)(bN + n) * KNN + k] = n;
        }
    }
}

// ---------------------------------------------------------------------------
extern "C" void kernel_launch(void* const* d_in, const int* in_sizes, int n_in,
                              void* d_out, int out_size, void* d_ws, size_t ws_size,
                              hipStream_t stream)
{
    const float* x = (const float*)d_in[0];
    int* out = (int*)d_out;

    char* ws = (char*)d_ws;
    const size_t sz_pk  = (size_t)BATCH * NTILE * KSTEP * 1024 * sizeof(unsigned short); // 12.58 MB
    const size_t sz_xrm = (size_t)BATCH * NPTS * CH * sizeof(float);                     // 12.58 MB
    const size_t sz_rdn = (size_t)BATCH * NPTS * sizeof(double);
    const size_t sz_ss  = sz_rdn;
    const size_t sz_ck  = (size_t)BATCH * NPTS * NCAND2 * sizeof(float);                 // 16.78 MB

    unsigned short* pk = (unsigned short*)(ws);
    float*  x_rm   = (float*) (ws + sz_pk);
    double* rdnd   = (double*)(ws + sz_pk + sz_xrm);
    double* ssd    = (double*)(ws + sz_pk + sz_xrm + sz_rdn);
    float*  cand_k = (float*) (ws + sz_pk + sz_xrm + sz_rdn + sz_ss);
    unsigned short* cand_i = (unsigned short*)(ws + sz_pk + sz_xrm + sz_rdn + sz_ss + sz_ck);

    knn_normalize<<<BATCH * (NPTS / NT), 256, 0, stream>>>(x, pk, x_rm, rdnd, ssd);
    knn_phase1  <<<BATCH * 64 * CSPLIT, 256, 0, stream>>>(pk, cand_k, cand_i);
    knn_phase2  <<<BATCH * (NPTS / 16), 256, 0, stream>>>(x_rm, rdnd, ssd, cand_k, cand_i, out);
}

// Round 5
// 428.142 us; speedup vs baseline: 3.7569x; 2.1067x over previous
//
#include <hip/hip_runtime.h>
#include <math.h>

#define BATCH 2
#define CH    192
#define NPTS  8192
#define KNN   9

#define NT     64      // rows per normalize block
#define TLIST  8       // per-bucket candidate list length
#define NTILE  512     // 16-wide row/col tiles per batch
#define KSTEP  6       // 192 / 32
#define CSPLIT 2       // column splits (phase 1)
#define CT     2       // col tiles staged per iteration
#define NITER  ((NTILE / CSPLIT) / CT)   // 128
#define NCAND2 256     // candidates per row total (2 splits * 16 bins * 8)
#define P2ROWS 4       // phase-2 rows per block (1 per wave)

typedef __attribute__((ext_vector_type(8))) short  bf16x8;
typedef __attribute__((ext_vector_type(8))) unsigned short u16x8;
typedef __attribute__((ext_vector_type(4))) float  f32x4;

static __device__ __forceinline__ unsigned short f2bf(float f) {
    unsigned u = __float_as_uint(f);
    u += 0x7fffu + ((u >> 16) & 1u);          // round-to-nearest-even
    return (unsigned short)(u >> 16);
}
static __device__ __forceinline__ float bf2f(unsigned short h) {
    return __uint_as_float(((unsigned)h) << 16);
}

// ---------------------------------------------------------------------------
// Kernel A: norms + layouts (unchanged — passing since R2).
//  pk    [B][tile(512)][ks(6)][half(2)][lane(64)*8] bf16  — MFMA frag layout
//        element: row = tile*16 + (lane&15), k = ks*32 + (lane>>4)*8 + e
// ---------------------------------------------------------------------------
__global__ __launch_bounds__(256) void knn_normalize(
    const float* __restrict__ x,
    unsigned short* __restrict__ pk, float* __restrict__ x_rm,
    double* __restrict__ rdnd, double* __restrict__ ssd)
{
    __shared__ float  tile[CH][NT + 1];
    __shared__ double rdn_sh[NT];

    const int b   = blockIdx.x >> 7;
    const int rb  = blockIdx.x & 127;
    const int n0  = rb << 6;
    const int tid = threadIdx.x;
    const float* xb = x + (size_t)b * CH * NPTS;

    #pragma unroll
    for (int i = 0; i < (CH * NT) / 256; ++i) {
        int flat = tid + i * 256;
        int c = flat >> 6, j = flat & 63;
        tile[c][j] = xb[(size_t)c * NPTS + n0 + j];
    }
    __syncthreads();

    if (tid < NT) {
        double ss = 0.0;
        #pragma unroll 8
        for (int c = 0; c < CH; ++c) {
            double v = (double)tile[c][tid];
            ss = fma(v, v, ss);
        }
        double dn = sqrt(ss);
        if (dn < 1e-12) dn = 1e-12;
        double rdn = 1.0 / dn;
        rdn_sh[tid] = rdn;
        rdnd[b * NPTS + n0 + tid] = rdn;
        ssd [b * NPTS + n0 + tid] = ss;
    }
    __syncthreads();

    #pragma unroll
    for (int i = 0; i < 6; ++i) {
        int pid  = tid + i * 256;
        int frag = pid >> 6;
        int lane = pid & 63;
        int tl   = frag / KSTEP;
        int ks   = frag - tl * KSTEP;
        int rl   = (tl << 4) + (lane & 15);
        int kb   = (ks << 5) + ((lane >> 4) << 3);
        double rdn = rdn_sh[rl];
        u16x8 hv, lv;
        #pragma unroll
        for (int e = 0; e < 8; ++e) {
            float v = (float)((double)tile[kb + e][rl] * rdn);
            unsigned short h = f2bf(v);
            hv[e] = h;
            lv[e] = f2bf(v - bf2f(h));
        }
        size_t base = ((size_t)((b * NTILE + (rb << 2) + tl) * KSTEP + ks)) * 1024
                      + ((size_t)lane << 3);
        *(u16x8*)(pk + base)       = hv;
        *(u16x8*)(pk + base + 512) = lv;
    }

    #pragma unroll
    for (int i = 0; i < (CH * NT) / 256; ++i) {
        int flat = tid + i * 256;
        int j = flat / CH, c = flat - j * CH;
        x_rm[(size_t)(b * NPTS + n0 + j) * CH + c] = tile[c][j];
    }
}

// ---------------------------------------------------------------------------
// Phase 1 (unchanged from R3 — passing): LDS-staged double-buffered bf16x3
// MFMA + register top-8 buckets. Bucket = (cs, col&15), depth 8 -> 256/row.
// ---------------------------------------------------------------------------
__global__ __launch_bounds__(256, 1) void knn_phase1(
    const unsigned short* __restrict__ pk,
    float* __restrict__ cand_k, unsigned short* __restrict__ cand_i)
{
    __shared__ unsigned short ldsB[2][CT * KSTEP * 1024];   // 2 x 24576 B

    const int bid  = blockIdx.x;
    const int b    = bid >> 7;
    const int r7   = bid & 127;
    const int rb   = r7 >> 1;         // row block (128 rows)
    const int cs   = r7 & 1;          // column split
    const int tid  = threadIdx.x;
    const int wave = tid >> 6;
    const int lane = tid & 63;
    const unsigned short* pkb = pk + (size_t)b * (NTILE * KSTEP * 1024);
    const int ct0 = cs * (NTILE / CSPLIT);

    bf16x8 a_hi[2][KSTEP], a_lo[2][KSTEP];
    #pragma unroll
    for (int ri = 0; ri < 2; ++ri) {
        const int rt = rb * 8 + wave * 2 + ri;
        #pragma unroll
        for (int ks = 0; ks < KSTEP; ++ks) {
            const unsigned short* p = pkb + ((size_t)(rt * KSTEP + ks)) * 1024 + (lane << 3);
            a_hi[ri][ks] = *(const bf16x8*)p;
            a_lo[ri][ks] = *(const bf16x8*)(p + 512);
        }
    }

    float kbuf[8][TLIST]; int ibuf[8][TLIST];
    float wmax[8]; int wpos[8];
    #pragma unroll
    for (int s = 0; s < 8; ++s) {
        wmax[s] = INFINITY; wpos[s] = 0;
        #pragma unroll
        for (int t = 0; t < TLIST; ++t) { kbuf[s][t] = INFINITY; ibuf[s][t] = 0; }
    }

    {
        const char* g = (const char*)(pkb + (size_t)ct0 * (KSTEP * 1024));
        #pragma unroll
        for (int k = 0; k < 6; ++k) {
            int off = (k * 256 + tid) * 16;
            __builtin_amdgcn_global_load_lds(
                (const __attribute__((address_space(1))) unsigned int*)(g + off),
                (__attribute__((address_space(3))) unsigned int*)((char*)&ldsB[0][0] + off),
                16, 0, 0);
        }
    }
    __syncthreads();

    for (int it = 0; it < NITER; ++it) {
        const int cur = it & 1;
        if (it + 1 < NITER) {
            const char* g = (const char*)(pkb + (size_t)(ct0 + (it + 1) * CT) * (KSTEP * 1024));
            #pragma unroll
            for (int k = 0; k < 6; ++k) {
                int off = (k * 256 + tid) * 16;
                __builtin_amdgcn_global_load_lds(
                    (const __attribute__((address_space(1))) unsigned int*)(g + off),
                    (__attribute__((address_space(3))) unsigned int*)((char*)&ldsB[cur ^ 1][0] + off),
                    16, 0, 0);
            }
        }

        f32x4 acc[2][CT];
        #pragma unroll
        for (int ri = 0; ri < 2; ++ri)
            #pragma unroll
            for (int j = 0; j < CT; ++j) acc[ri][j] = (f32x4){0.f, 0.f, 0.f, 0.f};

        #pragma unroll
        for (int ks = 0; ks < KSTEP; ++ks) {
            bf16x8 bh[CT], bl[CT];
            #pragma unroll
            for (int j = 0; j < CT; ++j) {
                const unsigned short* p = &ldsB[cur][(j * KSTEP + ks) * 1024 + (lane << 3)];
                bh[j] = *(const bf16x8*)p;
                bl[j] = *(const bf16x8*)(p + 512);
            }
            #pragma unroll
            for (int ri = 0; ri < 2; ++ri)
                #pragma unroll
                for (int j = 0; j < CT; ++j) {
                    acc[ri][j] = __builtin_amdgcn_mfma_f32_16x16x32_bf16(a_hi[ri][ks], bh[j], acc[ri][j], 0, 0, 0);
                    acc[ri][j] = __builtin_amdgcn_mfma_f32_16x16x32_bf16(a_hi[ri][ks], bl[j], acc[ri][j], 0, 0, 0);
                    acc[ri][j] = __builtin_amdgcn_mfma_f32_16x16x32_bf16(a_lo[ri][ks], bh[j], acc[ri][j], 0, 0, 0);
                }
        }

        const int colbase = ((ct0 + it * CT) << 4) + (lane & 15);
        #pragma unroll
        for (int ri = 0; ri < 2; ++ri)
            #pragma unroll
            for (int j = 0; j < CT; ++j) {
                const int col = colbase + (j << 4);
                #pragma unroll
                for (int s = 0; s < 4; ++s) {
                    const int sl = ri * 4 + s;
                    float key = -acc[ri][j][s];
                    if (key < wmax[sl]) {
                        #pragma unroll
                        for (int t = 0; t < TLIST; ++t)
                            if (t == wpos[sl]) { kbuf[sl][t] = key; ibuf[sl][t] = col; }
                        float nm = kbuf[sl][0]; int np_ = 0;
                        #pragma unroll
                        for (int t = 1; t < TLIST; ++t)
                            if (kbuf[sl][t] > nm) { nm = kbuf[sl][t]; np_ = t; }
                        wmax[sl] = nm; wpos[sl] = np_;
                    }
                }
            }
        __syncthreads();
    }

    #pragma unroll
    for (int ri = 0; ri < 2; ++ri) {
        const int rt = rb * 8 + wave * 2 + ri;
        #pragma unroll
        for (int s = 0; s < 4; ++s) {
            int row = (rt << 4) + ((lane >> 4) << 2) + s;
            size_t base = ((size_t)(b * NPTS + row) << 8) + (cs << 7) + ((lane & 15) << 3);
            #pragma unroll
            for (int t = 0; t < TLIST; ++t) {
                cand_k[base + t] = kbuf[ri * 4 + s][t];
                cand_i[base + t] = (unsigned short)ibuf[ri * 4 + s][t];
            }
        }
    }
}

// ---------------------------------------------------------------------------
// Phase 2: 1 row per wave, 4 rows/block, 4096 blocks.
//  (a) wave-parallel top-16-of-256 via packed-u64 shfl-min extraction
//  (b) f64 re-rank: lane=(cand,quarter), float4 gathers, 2-shfl reduce
//  (c) lane-0 serial 9-of-16 by (f64 key, idx)
// ---------------------------------------------------------------------------
__global__ __launch_bounds__(256) void knn_phase2(
    const float* __restrict__ x_rm,
    const double* __restrict__ rdnd, const double* __restrict__ ssd,
    const float* __restrict__ cand_k, const unsigned short* __restrict__ cand_i,
    int* __restrict__ out)
{
    __shared__ double xc[P2ROWS][CH];     // 6144 B
    __shared__ int    sel[P2ROWS][16];
    __shared__ double dks[P2ROWS][16];

    const int bi   = blockIdx.x;          // 4096
    const int b    = bi >> 11;
    const int r0   = (bi & 2047) << 2;
    const int tid  = threadIdx.x;
    const int wave = tid >> 6;
    const int lane = tid & 63;
    const int bN   = b * NPTS;

    // stage center rows as f64-normalized
    for (int i = tid; i < P2ROWS * CH; i += 256) {
        int r = i / CH, c = i - r * CH;
        xc[r][c] = (double)x_rm[(size_t)(bN + r0 + r) * CH + c] * rdnd[bN + r0 + r];
    }
    __syncthreads();

    const int row = r0 + wave;

    // (a) load 4 candidates per lane, pack into sortable u64 (key,id)
    unsigned long long pk0, pk1, pk2, pk3;
    {
        size_t base = (size_t)(bN + row) * NCAND2 + lane;
        unsigned long long pkt[4];
        #pragma unroll
        for (int u = 0; u < 4; ++u) {
            float k = cand_k[base + (u << 6)];
            unsigned id = cand_i[base + (u << 6)];
            unsigned kb = __float_as_uint(k);
            kb ^= (kb & 0x80000000u) ? 0xFFFFFFFFu : 0x80000000u;
            pkt[u] = ((unsigned long long)kb << 32) | id;
        }
        // sort 4 ascending: CE network (0,1)(2,3)(0,2)(1,3)(1,2)
        unsigned long long a0 = pkt[0], a1 = pkt[1], a2 = pkt[2], a3 = pkt[3], t;
        if (a1 < a0) { t = a0; a0 = a1; a1 = t; }
        if (a3 < a2) { t = a2; a2 = a3; a3 = t; }
        if (a2 < a0) { t = a0; a0 = a2; a2 = t; }
        if (a3 < a1) { t = a1; a1 = a3; a3 = t; }
        if (a2 < a1) { t = a1; a1 = a2; a2 = t; }
        pk0 = a0; pk1 = a1; pk2 = a2; pk3 = a3;
    }

    // 16 extraction rounds of wave-wide u64 min; lane r captures round r
    unsigned long long my_sel = 0;
    #pragma unroll
    for (int round = 0; round < 16; ++round) {
        unsigned long long m = pk0;
        #pragma unroll
        for (int off = 1; off < 64; off <<= 1) {
            unsigned long long o = __shfl_xor(m, off, 64);
            m = (o < m) ? o : m;
        }
        if (pk0 == m) {                 // exactly one lane (ids unique)
            pk0 = pk1; pk1 = pk2; pk2 = pk3;
            pk3 = 0xFFFFFFFFFFFFFFFFull;
        }
        if (lane == round) my_sel = m;
    }
    if (lane < 16) sel[wave][lane] = (int)(my_sel & 0xFFFFu);

    // (b) exact f64 keys: lane = (cand c, quarter q)
    {
        const int c = lane & 15, q = lane >> 4;
        const int m = sel[wave][c];
        const double rdm = rdnd[bN + m];
        const float* xr = x_rm + (size_t)(bN + m) * CH + q * 48;
        const double* xcp = &xc[wave][q * 48];
        double s0 = 0.0, s1 = 0.0, s2 = 0.0, s3 = 0.0;
        #pragma unroll
        for (int j = 0; j < 12; ++j) {
            float4 v = *(const float4*)(xr + (j << 2));
            s0 = fma((double)v.x * rdm, xcp[(j << 2) + 0], s0);
            s1 = fma((double)v.y * rdm, xcp[(j << 2) + 1], s1);
            s2 = fma((double)v.z * rdm, xcp[(j << 2) + 2], s2);
            s3 = fma((double)v.w * rdm, xcp[(j << 2) + 3], s3);
        }
        double dot = (s0 + s1) + (s2 + s3);
        dot += __shfl_xor(dot, 16, 64);
        dot += __shfl_xor(dot, 32, 64);
        if (q == 0) dks[wave][c] = fma(-2.0, dot, ssd[bN + m] * rdm * rdm);
    }

    // (c) 9 smallest of 16 by (key, idx) — serial on lane 0 of each wave
    if (lane == 0) {
        const int n = row;
        unsigned used = 0;
        for (int k = 0; k < KNN; ++k) {
            double bd = INFINITY; int bm = 0x7fffffff; int bp = 0;
            #pragma unroll
            for (int s = 0; s < 16; ++s) {
                if (!((used >> s) & 1u)) {
                    double d = dks[wave][s]; int m = sel[wave][s];
                    if (d < bd || (d == bd && m < bm)) { bd = d; bm = m; bp = s; }
                }
            }
            used |= (1u << bp);
            out[(size_t)(bN + n) * KNN + k] = bm;
            out[(size_t)BATCH * NPTS * KNN + (size_t)(bN + n) * KNN + k] = n;
        }
    }
}

// ---------------------------------------------------------------------------
extern "C" void kernel_launch(void* const* d_in, const int* in_sizes, int n_in,
                              void* d_out, int out_size, void* d_ws, size_t ws_size,
                              hipStream_t stream)
{
    const float* x = (const float*)d_in[0];
    int* out = (int*)d_out;

    char* ws = (char*)d_ws;
    const size_t sz_pk  = (size_t)BATCH * NTILE * KSTEP * 1024 * sizeof(unsigned short); // 12.58 MB
    const size_t sz_xrm = (size_t)BATCH * NPTS * CH * sizeof(float);                     // 12.58 MB
    const size_t sz_rdn = (size_t)BATCH * NPTS * sizeof(double);
    const size_t sz_ss  = sz_rdn;
    const size_t sz_ck  = (size_t)BATCH * NPTS * NCAND2 * sizeof(float);                 // 16.78 MB

    unsigned short* pk = (unsigned short*)(ws);
    float*  x_rm   = (float*) (ws + sz_pk);
    double* rdnd   = (double*)(ws + sz_pk + sz_xrm);
    double* ssd    = (double*)(ws + sz_pk + sz_xrm + sz_rdn);
    float*  cand_k = (float*) (ws + sz_pk + sz_xrm + sz_rdn + sz_ss);
    unsigned short* cand_i = (unsigned short*)(ws + sz_pk + sz_xrm + sz_rdn + sz_ss + sz_ck);

    knn_normalize<<<BATCH * (NPTS / NT), 256, 0, stream>>>(x, pk, x_rm, rdnd, ssd);
    knn_phase1  <<<BATCH * 64 * CSPLIT, 256, 0, stream>>>(pk, cand_k, cand_i);
    knn_phase2  <<<BATCH * (NPTS / P2ROWS), 256, 0, stream>>>(x_rm, rdnd, ssd, cand_k, cand_i, out);
}

// Round 6
// 272.614 us; speedup vs baseline: 5.9002x; 1.5705x over previous
//
#include <hip/hip_runtime.h>
#include <math.h>

#define BATCH 2
#define CH    192
#define NPTS  8192
#define KNN   9

#define NT     64      // rows per normalize block
#define TLIST  8       // per-bucket candidate list depth
#define NTILE  512     // 16-wide row/col tiles per batch
#define KSTEP  6       // 192 / 32
#define CSPLIT 4       // column splits (phase 1)
#define CT     2       // col tiles staged per iteration
#define NITER  ((NTILE / CSPLIT) / CT)   // 64
#define NCANDP 512     // packed candidates per row (4 cs * 16 bins * 8)
#define P2ROWS 4       // phase-2 rows per block (1 per wave)

typedef __attribute__((ext_vector_type(8))) short  bf16x8;
typedef __attribute__((ext_vector_type(8))) unsigned short u16x8;
typedef __attribute__((ext_vector_type(4))) float  f32x4;

static __device__ __forceinline__ unsigned short f2bf(float f) {
    unsigned u = __float_as_uint(f);
    u += 0x7fffu + ((u >> 16) & 1u);          // round-to-nearest-even
    return (unsigned short)(u >> 16);
}
static __device__ __forceinline__ float bf2f(unsigned short h) {
    return __uint_as_float(((unsigned)h) << 16);
}

// ---------------------------------------------------------------------------
// Kernel A: norms + layouts (unchanged — passing since R2).
//  pk    [B][tile(512)][ks(6)][half(2)][lane(64)*8] bf16  — MFMA frag layout
//        element: row = tile*16 + (lane&15), k = ks*32 + (lane>>4)*8 + e
// ---------------------------------------------------------------------------
__global__ __launch_bounds__(256) void knn_normalize(
    const float* __restrict__ x,
    unsigned short* __restrict__ pk, float* __restrict__ x_rm,
    double* __restrict__ rdnd, double* __restrict__ ssd)
{
    __shared__ float  tile[CH][NT + 1];
    __shared__ double rdn_sh[NT];

    const int b   = blockIdx.x >> 7;
    const int rb  = blockIdx.x & 127;
    const int n0  = rb << 6;
    const int tid = threadIdx.x;
    const float* xb = x + (size_t)b * CH * NPTS;

    #pragma unroll
    for (int i = 0; i < (CH * NT) / 256; ++i) {
        int flat = tid + i * 256;
        int c = flat >> 6, j = flat & 63;
        tile[c][j] = xb[(size_t)c * NPTS + n0 + j];
    }
    __syncthreads();

    if (tid < NT) {
        double ss = 0.0;
        #pragma unroll 8
        for (int c = 0; c < CH; ++c) {
            double v = (double)tile[c][tid];
            ss = fma(v, v, ss);
        }
        double dn = sqrt(ss);
        if (dn < 1e-12) dn = 1e-12;
        double rdn = 1.0 / dn;
        rdn_sh[tid] = rdn;
        rdnd[b * NPTS + n0 + tid] = rdn;
        ssd [b * NPTS + n0 + tid] = ss;
    }
    __syncthreads();

    #pragma unroll
    for (int i = 0; i < 6; ++i) {
        int pid  = tid + i * 256;
        int frag = pid >> 6;
        int lane = pid & 63;
        int tl   = frag / KSTEP;
        int ks   = frag - tl * KSTEP;
        int rl   = (tl << 4) + (lane & 15);
        int kb   = (ks << 5) + ((lane >> 4) << 3);
        double rdn = rdn_sh[rl];
        u16x8 hv, lv;
        #pragma unroll
        for (int e = 0; e < 8; ++e) {
            float v = (float)((double)tile[kb + e][rl] * rdn);
            unsigned short h = f2bf(v);
            hv[e] = h;
            lv[e] = f2bf(v - bf2f(h));
        }
        size_t base = ((size_t)((b * NTILE + (rb << 2) + tl) * KSTEP + ks)) * 1024
                      + ((size_t)lane << 3);
        *(u16x8*)(pk + base)       = hv;
        *(u16x8*)(pk + base + 512) = lv;
    }

    #pragma unroll
    for (int i = 0; i < (CH * NT) / 256; ++i) {
        int flat = tid + i * 256;
        int j = flat / CH, c = flat - j * CH;
        x_rm[(size_t)(b * NPTS + n0 + j) * CH + c] = tile[c][j];
    }
}

// ---------------------------------------------------------------------------
// Phase 1 v3: 512 blocks (2/CU), 2 row tiles per wave, CT=2 staged via
// global_load_lds (double-buffered 48 KB). Selection on packed u32
// (24-bit descending-inner key | 7-bit local tile), replace-equal-to-max.
// Bucket = (cs, col&15): 64 buckets x depth 8 = 512 candidates/row.
// ---------------------------------------------------------------------------
__global__ __launch_bounds__(256, 2) void knn_phase1(
    const unsigned short* __restrict__ pk,
    unsigned* __restrict__ cand_p)
{
    __shared__ unsigned short ldsB[2][CT * KSTEP * 1024];   // 2 x 24576 B

    const int bid  = blockIdx.x;          // 512
    const int b    = bid >> 8;
    const int r8   = bid & 255;
    const int rb   = r8 >> 2;             // row block (128 rows), 0..63
    const int cs   = r8 & 3;              // column split, 0..3
    const int tid  = threadIdx.x;
    const int wave = tid >> 6;
    const int lane = tid & 63;
    const unsigned short* pkb = pk + (size_t)b * (NTILE * KSTEP * 1024);
    const int ct0 = cs * (NTILE / CSPLIT);       // 128 tiles per split

    // A fragments: 2 row tiles per wave
    bf16x8 a_hi[2][KSTEP], a_lo[2][KSTEP];
    #pragma unroll
    for (int ri = 0; ri < 2; ++ri) {
        const int rt = rb * 8 + wave * 2 + ri;
        #pragma unroll
        for (int ks = 0; ks < KSTEP; ++ks) {
            const unsigned short* p = pkb + ((size_t)(rt * KSTEP + ks)) * 1024 + (lane << 3);
            a_hi[ri][ks] = *(const bf16x8*)p;
            a_lo[ri][ks] = *(const bf16x8*)(p + 512);
        }
    }

    // packed candidate lists: distinct sentinels (all real packed < 0xF0000000)
    unsigned lst[8][TLIST];
    unsigned wmax[8];
    #pragma unroll
    for (int s = 0; s < 8; ++s) {
        #pragma unroll
        for (int t = 0; t < TLIST; ++t) lst[s][t] = 0xFFFFFF00u | t;
        wmax[s] = 0xFFFFFF00u | (TLIST - 1);
    }

    // prologue stage of buffer 0
    {
        const char* g = (const char*)(pkb + (size_t)ct0 * (KSTEP * 1024));
        #pragma unroll
        for (int k = 0; k < 6; ++k) {
            int off = (k * 256 + tid) * 16;
            __builtin_amdgcn_global_load_lds(
                (const __attribute__((address_space(1))) unsigned int*)(g + off),
                (__attribute__((address_space(3))) unsigned int*)((char*)&ldsB[0][0] + off),
                16, 0, 0);
        }
    }
    __syncthreads();

    for (int it = 0; it < NITER; ++it) {
        const int cur = it & 1;
        if (it + 1 < NITER) {
            const char* g = (const char*)(pkb + (size_t)(ct0 + (it + 1) * CT) * (KSTEP * 1024));
            #pragma unroll
            for (int k = 0; k < 6; ++k) {
                int off = (k * 256 + tid) * 16;
                __builtin_amdgcn_global_load_lds(
                    (const __attribute__((address_space(1))) unsigned int*)(g + off),
                    (__attribute__((address_space(3))) unsigned int*)((char*)&ldsB[cur ^ 1][0] + off),
                    16, 0, 0);
            }
        }

        f32x4 acc[2][CT];
        #pragma unroll
        for (int ri = 0; ri < 2; ++ri)
            #pragma unroll
            for (int j = 0; j < CT; ++j) acc[ri][j] = (f32x4){0.f, 0.f, 0.f, 0.f};

        #pragma unroll
        for (int ks = 0; ks < KSTEP; ++ks) {
            bf16x8 bh[CT], bl[CT];
            #pragma unroll
            for (int j = 0; j < CT; ++j) {
                const unsigned short* p = &ldsB[cur][(j * KSTEP + ks) * 1024 + (lane << 3)];
                bh[j] = *(const bf16x8*)p;
                bl[j] = *(const bf16x8*)(p + 512);
            }
            #pragma unroll
            for (int ri = 0; ri < 2; ++ri)
                #pragma unroll
                for (int j = 0; j < CT; ++j) {
                    acc[ri][j] = __builtin_amdgcn_mfma_f32_16x16x32_bf16(a_hi[ri][ks], bh[j], acc[ri][j], 0, 0, 0);
                    acc[ri][j] = __builtin_amdgcn_mfma_f32_16x16x32_bf16(a_hi[ri][ks], bl[j], acc[ri][j], 0, 0, 0);
                    acc[ri][j] = __builtin_amdgcn_mfma_f32_16x16x32_bf16(a_lo[ri][ks], bh[j], acc[ri][j], 0, 0, 0);
                }
        }

        // selection: packed = (desc-sortable(acc) & 0xFFFFFF80) | local tile
        #pragma unroll
        for (int ri = 0; ri < 2; ++ri)
            #pragma unroll
            for (int j = 0; j < CT; ++j) {
                const unsigned ctl = (unsigned)(it * CT + j);   // 0..127
                #pragma unroll
                for (int s = 0; s < 4; ++s) {
                    const int sl = ri * 4 + s;
                    unsigned u = __float_as_uint(acc[ri][j][s]);
                    unsigned g = u ^ (~(unsigned)((int)u >> 31) & 0x7FFFFFFFu);
                    unsigned p = (g & 0xFFFFFF80u) | ctl;
                    if (p < wmax[sl]) {
                        const unsigned wm = wmax[sl];
                        #pragma unroll
                        for (int t = 0; t < TLIST; ++t)
                            lst[sl][t] = (lst[sl][t] == wm) ? p : lst[sl][t];
                        unsigned m0 = lst[sl][0] > lst[sl][1] ? lst[sl][0] : lst[sl][1];
                        unsigned m1 = lst[sl][2] > lst[sl][3] ? lst[sl][2] : lst[sl][3];
                        unsigned m2 = lst[sl][4] > lst[sl][5] ? lst[sl][4] : lst[sl][5];
                        unsigned m3 = lst[sl][6] > lst[sl][7] ? lst[sl][6] : lst[sl][7];
                        m0 = m0 > m1 ? m0 : m1;
                        m2 = m2 > m3 ? m2 : m3;
                        wmax[sl] = m0 > m2 ? m0 : m2;
                    }
                }
            }
        __syncthreads();
    }

    // write candidates: [B*N][512], slot = cs*128 + bin*8 + t
    const int bin = lane & 15;
    #pragma unroll
    for (int ri = 0; ri < 2; ++ri) {
        const int rt = rb * 8 + wave * 2 + ri;
        #pragma unroll
        for (int s = 0; s < 4; ++s) {
            int row = (rt << 4) + ((lane >> 4) << 2) + s;
            size_t base = ((size_t)(b * NPTS + row) << 9) + (cs << 7) + (bin << 3);
            #pragma unroll
            for (int t = 0; t < TLIST; ++t)
                cand_p[base + t] = lst[ri * 4 + s][t];
        }
    }
}

// ---------------------------------------------------------------------------
// Phase 2: 1 row per wave, 4 rows/block, 4096 blocks.
//  (a) per-lane sort-8 of packed u64 (key||col), 16-round wave-min extraction
//  (b) f64 re-rank: lane=(cand,quarter), float4 gathers, 2-shfl reduce
//  (c) lane-0 serial 9-of-16 by (f64 key, idx)
// ---------------------------------------------------------------------------
__global__ __launch_bounds__(256) void knn_phase2(
    const float* __restrict__ x_rm,
    const double* __restrict__ rdnd, const double* __restrict__ ssd,
    const unsigned* __restrict__ cand_p,
    int* __restrict__ out)
{
    __shared__ double xc[P2ROWS][CH];     // 6144 B
    __shared__ int    sel[P2ROWS][16];
    __shared__ double dks[P2ROWS][16];

    const int bi   = blockIdx.x;          // 4096
    const int b    = bi >> 11;
    const int r0   = (bi & 2047) << 2;
    const int tid  = threadIdx.x;
    const int wave = tid >> 6;
    const int lane = tid & 63;
    const int bN   = b * NPTS;

    for (int i = tid; i < P2ROWS * CH; i += 256) {
        int r = i / CH, c = i - r * CH;
        xc[r][c] = (double)x_rm[(size_t)(bN + r0 + r) * CH + c] * rdnd[bN + r0 + r];
    }
    __syncthreads();

    const int row = r0 + wave;

    // (a) load 8 packed candidates per lane, reconstruct col, sort ascending
    unsigned long long q0, q1, q2, q3, q4, q5, q6, q7;
    {
        unsigned long long qq[8];
        size_t base = (size_t)(bN + row) * NCANDP + lane;
        #pragma unroll
        for (int u = 0; u < 8; ++u) {
            int ss = lane + (u << 6);
            unsigned pkv = cand_p[base + (u << 6)];
            int csq = ss >> 7, bin = (ss >> 3) & 15;
            int col = ((csq << 7) | (int)(pkv & 0x7Fu)) * 16 + bin;
            qq[u] = ((unsigned long long)pkv << 32) | (unsigned)col;
        }
        // Batcher odd-even merge sort for 8 (19 CE)
        unsigned long long t;
        #define CE(a, b) if (qq[b] < qq[a]) { t = qq[a]; qq[a] = qq[b]; qq[b] = t; }
        CE(0,1) CE(2,3) CE(4,5) CE(6,7)
        CE(0,2) CE(1,3) CE(4,6) CE(5,7)
        CE(1,2) CE(5,6)
        CE(0,4) CE(1,5) CE(2,6) CE(3,7)
        CE(2,4) CE(3,5)
        CE(1,2) CE(3,4) CE(5,6)
        #undef CE
        q0 = qq[0]; q1 = qq[1]; q2 = qq[2]; q3 = qq[3];
        q4 = qq[4]; q5 = qq[5]; q6 = qq[6]; q7 = qq[7];
    }

    // 16 extraction rounds of wave-wide u64 min; lane r captures round r
    unsigned long long my_sel = 0;
    #pragma unroll
    for (int round = 0; round < 16; ++round) {
        unsigned long long m = q0;
        #pragma unroll
        for (int off = 1; off < 64; off <<= 1) {
            unsigned long long o = __shfl_xor(m, off, 64);
            m = (o < m) ? o : m;
        }
        if (q0 == m) {                 // exactly one lane (cols unique)
            q0 = q1; q1 = q2; q2 = q3; q3 = q4; q4 = q5; q5 = q6; q6 = q7;
            q7 = 0xFFFFFFFFFFFFFFFFull;
        }
        if (lane == round) my_sel = m;
    }
    if (lane < 16) sel[wave][lane] = (int)((unsigned)my_sel & 0x3FFFu);
    __builtin_amdgcn_wave_barrier();

    // (b) exact f64 keys: lane = (cand c, quarter qd)
    {
        const int c = lane & 15, qd = lane >> 4;
        const int m = sel[wave][c];
        const double rdm = rdnd[bN + m];
        const float* xr = x_rm + (size_t)(bN + m) * CH + qd * 48;
        const double* xcp = &xc[wave][qd * 48];
        double s0 = 0.0, s1 = 0.0, s2 = 0.0, s3 = 0.0;
        #pragma unroll
        for (int j = 0; j < 12; ++j) {
            float4 v = *(const float4*)(xr + (j << 2));
            s0 = fma((double)v.x * rdm, xcp[(j << 2) + 0], s0);
            s1 = fma((double)v.y * rdm, xcp[(j << 2) + 1], s1);
            s2 = fma((double)v.z * rdm, xcp[(j << 2) + 2], s2);
            s3 = fma((double)v.w * rdm, xcp[(j << 2) + 3], s3);
        }
        double dot = (s0 + s1) + (s2 + s3);
        dot += __shfl_xor(dot, 16, 64);
        dot += __shfl_xor(dot, 32, 64);
        if (qd == 0) dks[wave][c] = fma(-2.0, dot, ssd[bN + m] * rdm * rdm);
    }

    // (c) 9 smallest of 16 by (key, idx) — serial on lane 0 of each wave
    if (lane == 0) {
        const int n = row;
        unsigned used = 0;
        for (int k = 0; k < KNN; ++k) {
            double bd = INFINITY; int bm = 0x7fffffff; int bp = 0;
            #pragma unroll
            for (int s = 0; s < 16; ++s) {
                if (!((used >> s) & 1u)) {
                    double d = dks[wave][s]; int m = sel[wave][s];
                    if (d < bd || (d == bd && m < bm)) { bd = d; bm = m; bp = s; }
                }
            }
            used |= (1u << bp);
            out[(size_t)(bN + n) * KNN + k] = bm;
            out[(size_t)BATCH * NPTS * KNN + (size_t)(bN + n) * KNN + k] = n;
        }
    }
}

// ---------------------------------------------------------------------------
extern "C" void kernel_launch(void* const* d_in, const int* in_sizes, int n_in,
                              void* d_out, int out_size, void* d_ws, size_t ws_size,
                              hipStream_t stream)
{
    const float* x = (const float*)d_in[0];
    int* out = (int*)d_out;

    char* ws = (char*)d_ws;
    const size_t sz_pk  = (size_t)BATCH * NTILE * KSTEP * 1024 * sizeof(unsigned short); // 12.58 MB
    const size_t sz_xrm = (size_t)BATCH * NPTS * CH * sizeof(float);                     // 12.58 MB
    const size_t sz_rdn = (size_t)BATCH * NPTS * sizeof(double);
    const size_t sz_ss  = sz_rdn;

    unsigned short* pk = (unsigned short*)(ws);
    float*  x_rm   = (float*) (ws + sz_pk);
    double* rdnd   = (double*)(ws + sz_pk + sz_xrm);
    double* ssd    = (double*)(ws + sz_pk + sz_xrm + sz_rdn);
    unsigned* cand_p = (unsigned*)(ws + sz_pk + sz_xrm + sz_rdn + sz_ss);                // 33.55 MB

    knn_normalize<<<BATCH * (NPTS / NT), 256, 0, stream>>>(x, pk, x_rm, rdnd, ssd);
    knn_phase1  <<<BATCH * 64 * CSPLIT, 256, 0, stream>>>(pk, cand_p);
    knn_phase2  <<<BATCH * (NPTS / P2ROWS), 256, 0, stream>>>(x_rm, rdnd, ssd, cand_p, out);
}

// Round 7
// 244.752 us; speedup vs baseline: 6.5719x; 1.1138x over previous
//
#include <hip/hip_runtime.h>
#include <math.h>

#define BATCH 2
#define CH    192
#define NPTS  8192
#define KNN   9

#define NT     64      // rows per normalize block
#define TLIST  6       // per-bucket candidate list depth
#define NTILE  512     // 16-wide row/col tiles per batch
#define KSTEP  6       // 192 / 32
#define CSPLIT 4       // column splits (phase 1)
#define CT     2       // col tiles staged per iteration
#define NITER  ((NTILE / CSPLIT) / CT)   // 64
#define NCANDP 384     // packed candidates per row (4 cs * 16 bins * 6)
#define P2ROWS 4       // phase-2 rows per block (1 per wave)

typedef __attribute__((ext_vector_type(8))) short  bf16x8;
typedef __attribute__((ext_vector_type(8))) unsigned short u16x8;
typedef __attribute__((ext_vector_type(4))) float  f32x4;

static __device__ __forceinline__ unsigned short f2bf(float f) {
    unsigned u = __float_as_uint(f);
    u += 0x7fffu + ((u >> 16) & 1u);          // round-to-nearest-even
    return (unsigned short)(u >> 16);
}
static __device__ __forceinline__ float bf2f(unsigned short h) {
    return __uint_as_float(((unsigned)h) << 16);
}
static __device__ __forceinline__ bf16x8 negbf(bf16x8 v) {
    bf16x8 r;
    #pragma unroll
    for (int e = 0; e < 8; ++e) r[e] = (short)(v[e] ^ (short)0x8000);
    return r;
}
static __device__ __forceinline__ unsigned umax2(unsigned a, unsigned b) {
    return a > b ? a : b;
}

// ---------------------------------------------------------------------------
// Kernel A: norms + layouts (unchanged — passing since R2).
//  pk    [B][tile(512)][ks(6)][half(2)][lane(64)*8] bf16  — MFMA frag layout
//        element: row = tile*16 + (lane&15), k = ks*32 + (lane>>4)*8 + e
// ---------------------------------------------------------------------------
__global__ __launch_bounds__(256) void knn_normalize(
    const float* __restrict__ x,
    unsigned short* __restrict__ pk, float* __restrict__ x_rm,
    double* __restrict__ rdnd, double* __restrict__ ssd)
{
    __shared__ float  tile[CH][NT + 1];
    __shared__ double rdn_sh[NT];

    const int b   = blockIdx.x >> 7;
    const int rb  = blockIdx.x & 127;
    const int n0  = rb << 6;
    const int tid = threadIdx.x;
    const float* xb = x + (size_t)b * CH * NPTS;

    #pragma unroll
    for (int i = 0; i < (CH * NT) / 256; ++i) {
        int flat = tid + i * 256;
        int c = flat >> 6, j = flat & 63;
        tile[c][j] = xb[(size_t)c * NPTS + n0 + j];
    }
    __syncthreads();

    if (tid < NT) {
        double ss = 0.0;
        #pragma unroll 8
        for (int c = 0; c < CH; ++c) {
            double v = (double)tile[c][tid];
            ss = fma(v, v, ss);
        }
        double dn = sqrt(ss);
        if (dn < 1e-12) dn = 1e-12;
        double rdn = 1.0 / dn;
        rdn_sh[tid] = rdn;
        rdnd[b * NPTS + n0 + tid] = rdn;
        ssd [b * NPTS + n0 + tid] = ss;
    }
    __syncthreads();

    #pragma unroll
    for (int i = 0; i < 6; ++i) {
        int pid  = tid + i * 256;
        int frag = pid >> 6;
        int lane = pid & 63;
        int tl   = frag / KSTEP;
        int ks   = frag - tl * KSTEP;
        int rl   = (tl << 4) + (lane & 15);
        int kb   = (ks << 5) + ((lane >> 4) << 3);
        double rdn = rdn_sh[rl];
        u16x8 hv, lv;
        #pragma unroll
        for (int e = 0; e < 8; ++e) {
            float v = (float)((double)tile[kb + e][rl] * rdn);
            unsigned short h = f2bf(v);
            hv[e] = h;
            lv[e] = f2bf(v - bf2f(h));
        }
        size_t base = ((size_t)((b * NTILE + (rb << 2) + tl) * KSTEP + ks)) * 1024
                      + ((size_t)lane << 3);
        *(u16x8*)(pk + base)       = hv;
        *(u16x8*)(pk + base + 512) = lv;
    }

    #pragma unroll
    for (int i = 0; i < (CH * NT) / 256; ++i) {
        int flat = tid + i * 256;
        int j = flat / CH, c = flat - j * CH;
        x_rm[(size_t)(b * NPTS + n0 + j) * CH + c] = tile[c][j];
    }
}

// ---------------------------------------------------------------------------
// Phase 1 v4: negated-A bias-4 keys (acc = 4 - inner, positive floats ->
// uint order == float order; pack = 1x v_and_or_b32). Depth-6 lists,
// replace-equal-to-max with max3-friendly tree. Structure else as R6.
// Bucket = (cs, col&15): 64 buckets x 6 = 384 candidates/row.
// ---------------------------------------------------------------------------
__global__ __launch_bounds__(256, 2) void knn_phase1(
    const unsigned short* __restrict__ pk,
    unsigned* __restrict__ cand_p)
{
    __shared__ unsigned short ldsB[2][CT * KSTEP * 1024];   // 2 x 24576 B

    const int bid  = blockIdx.x;          // 512
    const int b    = bid >> 8;
    const int r8   = bid & 255;
    const int rb   = r8 >> 2;             // row block (128 rows), 0..63
    const int cs   = r8 & 3;              // column split, 0..3
    const int tid  = threadIdx.x;
    const int wave = tid >> 6;
    const int lane = tid & 63;
    const unsigned short* pkb = pk + (size_t)b * (NTILE * KSTEP * 1024);
    const int ct0 = cs * (NTILE / CSPLIT);       // 128 tiles per split

    // A fragments: 2 row tiles per wave, NEGATED (for acc = 4 - inner)
    bf16x8 a_hi[2][KSTEP], a_lo[2][KSTEP];
    #pragma unroll
    for (int ri = 0; ri < 2; ++ri) {
        const int rt = rb * 8 + wave * 2 + ri;
        #pragma unroll
        for (int ks = 0; ks < KSTEP; ++ks) {
            const unsigned short* p = pkb + ((size_t)(rt * KSTEP + ks)) * 1024 + (lane << 3);
            a_hi[ri][ks] = negbf(*(const bf16x8*)p);
            a_lo[ri][ks] = negbf(*(const bf16x8*)(p + 512));
        }
    }

    // packed lists; sentinels above all real keys (real < 0x40C00000)
    unsigned lst[8][TLIST];
    unsigned wmax[8];
    #pragma unroll
    for (int s = 0; s < 8; ++s) {
        #pragma unroll
        for (int t = 0; t < TLIST; ++t) lst[s][t] = 0xFFFFFF00u | t;
        wmax[s] = 0xFFFFFF00u | (TLIST - 1);
    }

    // prologue stage of buffer 0
    {
        const char* g = (const char*)(pkb + (size_t)ct0 * (KSTEP * 1024));
        #pragma unroll
        for (int k = 0; k < 6; ++k) {
            int off = (k * 256 + tid) * 16;
            __builtin_amdgcn_global_load_lds(
                (const __attribute__((address_space(1))) unsigned int*)(g + off),
                (__attribute__((address_space(3))) unsigned int*)((char*)&ldsB[0][0] + off),
                16, 0, 0);
        }
    }
    __syncthreads();

    for (int it = 0; it < NITER; ++it) {
        const int cur = it & 1;
        if (it + 1 < NITER) {
            const char* g = (const char*)(pkb + (size_t)(ct0 + (it + 1) * CT) * (KSTEP * 1024));
            #pragma unroll
            for (int k = 0; k < 6; ++k) {
                int off = (k * 256 + tid) * 16;
                __builtin_amdgcn_global_load_lds(
                    (const __attribute__((address_space(1))) unsigned int*)(g + off),
                    (__attribute__((address_space(3))) unsigned int*)((char*)&ldsB[cur ^ 1][0] + off),
                    16, 0, 0);
            }
        }

        f32x4 acc[2][CT];
        #pragma unroll
        for (int ri = 0; ri < 2; ++ri)
            #pragma unroll
            for (int j = 0; j < CT; ++j) acc[ri][j] = (f32x4){4.f, 4.f, 4.f, 4.f};

        #pragma unroll
        for (int ks = 0; ks < KSTEP; ++ks) {
            bf16x8 bh[CT], bl[CT];
            #pragma unroll
            for (int j = 0; j < CT; ++j) {
                const unsigned short* p = &ldsB[cur][(j * KSTEP + ks) * 1024 + (lane << 3)];
                bh[j] = *(const bf16x8*)p;
                bl[j] = *(const bf16x8*)(p + 512);
            }
            #pragma unroll
            for (int ri = 0; ri < 2; ++ri)
                #pragma unroll
                for (int j = 0; j < CT; ++j) {
                    acc[ri][j] = __builtin_amdgcn_mfma_f32_16x16x32_bf16(a_hi[ri][ks], bh[j], acc[ri][j], 0, 0, 0);
                    acc[ri][j] = __builtin_amdgcn_mfma_f32_16x16x32_bf16(a_hi[ri][ks], bl[j], acc[ri][j], 0, 0, 0);
                    acc[ri][j] = __builtin_amdgcn_mfma_f32_16x16x32_bf16(a_lo[ri][ks], bh[j], acc[ri][j], 0, 0, 0);
                }
        }

        // selection: key = 4 - inner (positive) -> p = (bits & ~0x7F) | tile
        #pragma unroll
        for (int ri = 0; ri < 2; ++ri)
            #pragma unroll
            for (int j = 0; j < CT; ++j) {
                const unsigned ctl = (unsigned)(it * CT + j);   // 0..127
                #pragma unroll
                for (int s = 0; s < 4; ++s) {
                    const int sl = ri * 4 + s;
                    unsigned p = (__float_as_uint(acc[ri][j][s]) & 0xFFFFFF80u) | ctl;
                    const unsigned wm = wmax[sl];
                    if (p < wm) {
                        #pragma unroll
                        for (int t = 0; t < TLIST; ++t)
                            lst[sl][t] = (lst[sl][t] == wm) ? p : lst[sl][t];
                        unsigned m0 = umax2(umax2(lst[sl][0], lst[sl][1]), lst[sl][2]);
                        unsigned m1 = umax2(umax2(lst[sl][3], lst[sl][4]), lst[sl][5]);
                        wmax[sl] = umax2(m0, m1);
                    }
                }
            }
        __syncthreads();
    }

    // write candidates: [B*N][384], slot = cs*96 + bin*6 + t
    const int bin = lane & 15;
    #pragma unroll
    for (int ri = 0; ri < 2; ++ri) {
        const int rt = rb * 8 + wave * 2 + ri;
        #pragma unroll
        for (int s = 0; s < 4; ++s) {
            int row = (rt << 4) + ((lane >> 4) << 2) + s;
            size_t base = (size_t)(b * NPTS + row) * NCANDP + cs * 96 + bin * 6;
            #pragma unroll
            for (int t = 0; t < TLIST; ++t)
                cand_p[base + t] = lst[ri * 4 + s][t];
        }
    }
}

// ---------------------------------------------------------------------------
// Phase 2: 1 row per wave, 4 rows/block, 4096 blocks.
//  (a) per-lane sorted-6 (one bucket/lane), 16-round wave-min extraction
//  (b) f64 re-rank: lane=(cand,quarter), float4 gathers, 2-shfl reduce
//  (c) lane-0 serial 9-of-16 by (f64 key, idx)
// ---------------------------------------------------------------------------
__global__ __launch_bounds__(256) void knn_phase2(
    const float* __restrict__ x_rm,
    const double* __restrict__ rdnd, const double* __restrict__ ssd,
    const unsigned* __restrict__ cand_p,
    int* __restrict__ out)
{
    __shared__ double xc[P2ROWS][CH];     // 6144 B
    __shared__ int    sel[P2ROWS][16];
    __shared__ double dks[P2ROWS][16];

    const int bi   = blockIdx.x;          // 4096
    const int b    = bi >> 11;
    const int r0   = (bi & 2047) << 2;
    const int tid  = threadIdx.x;
    const int wave = tid >> 6;
    const int lane = tid & 63;
    const int bN   = b * NPTS;

    for (int i = tid; i < P2ROWS * CH; i += 256) {
        int r = i / CH, c = i - r * CH;
        xc[r][c] = (double)x_rm[(size_t)(bN + r0 + r) * CH + c] * rdnd[bN + r0 + r];
    }
    __syncthreads();

    const int row = r0 + wave;

    // (a) lane's bucket: cs = lane>>4, bin = lane&15; 6 packed u32 -> u64
    unsigned long long q0, q1, q2, q3, q4, q5;
    {
        unsigned long long qq[6];
        const unsigned* cp = cand_p + (size_t)(bN + row) * NCANDP + lane * 6;
        const int csq = lane >> 4, bin = lane & 15;
        #pragma unroll
        for (int u = 0; u < 6; ++u) {
            unsigned pkv = cp[u];
            int col = (csq << 11) + (int)(pkv & 0x7Fu) * 16 + bin;  // cs*128 tiles *16
            qq[u] = ((unsigned long long)pkv << 32) | (unsigned)col;
        }
        // sort6 ascending, 12-CE network
        unsigned long long t;
        #define CE(a, b) if (qq[b] < qq[a]) { t = qq[a]; qq[a] = qq[b]; qq[b] = t; }
        CE(0,5) CE(1,3) CE(2,4)
        CE(1,2) CE(3,4)
        CE(0,3) CE(2,5)
        CE(0,1) CE(2,3) CE(4,5)
        CE(1,2) CE(3,4)
        #undef CE
        q0 = qq[0]; q1 = qq[1]; q2 = qq[2]; q3 = qq[3]; q4 = qq[4]; q5 = qq[5];
    }

    // 16 extraction rounds of wave-wide u64 min; lane r captures round r
    unsigned long long my_sel = 0;
    #pragma unroll
    for (int round = 0; round < 16; ++round) {
        unsigned long long m = q0;
        #pragma unroll
        for (int off = 1; off < 64; off <<= 1) {
            unsigned long long o = __shfl_xor(m, off, 64);
            m = (o < m) ? o : m;
        }
        if (q0 == m) {                 // exactly one lane (u64 unique via col)
            q0 = q1; q1 = q2; q2 = q3; q3 = q4; q4 = q5;
            q5 = 0xFFFFFFFFFFFFFFFFull;
        }
        if (lane == round) my_sel = m;
    }
    if (lane < 16) sel[wave][lane] = (int)((unsigned)my_sel & 0x3FFFu);
    __builtin_amdgcn_wave_barrier();

    // (b) exact f64 keys: lane = (cand c, quarter qd)
    {
        const int c = lane & 15, qd = lane >> 4;
        const int m = sel[wave][c];
        const double rdm = rdnd[bN + m];
        const float* xr = x_rm + (size_t)(bN + m) * CH + qd * 48;
        const double* xcp = &xc[wave][qd * 48];
        double s0 = 0.0, s1 = 0.0, s2 = 0.0, s3 = 0.0;
        #pragma unroll
        for (int j = 0; j < 12; ++j) {
            float4 v = *(const float4*)(xr + (j << 2));
            s0 = fma((double)v.x * rdm, xcp[(j << 2) + 0], s0);
            s1 = fma((double)v.y * rdm, xcp[(j << 2) + 1], s1);
            s2 = fma((double)v.z * rdm, xcp[(j << 2) + 2], s2);
            s3 = fma((double)v.w * rdm, xcp[(j << 2) + 3], s3);
        }
        double dot = (s0 + s1) + (s2 + s3);
        dot += __shfl_xor(dot, 16, 64);
        dot += __shfl_xor(dot, 32, 64);
        if (qd == 0) dks[wave][c] = fma(-2.0, dot, ssd[bN + m] * rdm * rdm);
    }
    __builtin_amdgcn_wave_barrier();

    // (c) 9 smallest of 16 by (key, idx) — serial on lane 0 of each wave
    if (lane == 0) {
        const int n = row;
        unsigned used = 0;
        for (int k = 0; k < KNN; ++k) {
            double bd = INFINITY; int bm = 0x7fffffff; int bp = 0;
            #pragma unroll
            for (int s = 0; s < 16; ++s) {
                if (!((used >> s) & 1u)) {
                    double d = dks[wave][s]; int m = sel[wave][s];
                    if (d < bd || (d == bd && m < bm)) { bd = d; bm = m; bp = s; }
                }
            }
            used |= (1u << bp);
            out[(size_t)(bN + n) * KNN + k] = bm;
            out[(size_t)BATCH * NPTS * KNN + (size_t)(bN + n) * KNN + k] = n;
        }
    }
}

// ---------------------------------------------------------------------------
extern "C" void kernel_launch(void* const* d_in, const int* in_sizes, int n_in,
                              void* d_out, int out_size, void* d_ws, size_t ws_size,
                              hipStream_t stream)
{
    const float* x = (const float*)d_in[0];
    int* out = (int*)d_out;

    char* ws = (char*)d_ws;
    const size_t sz_pk  = (size_t)BATCH * NTILE * KSTEP * 1024 * sizeof(unsigned short); // 12.58 MB
    const size_t sz_xrm = (size_t)BATCH * NPTS * CH * sizeof(float);                     // 12.58 MB
    const size_t sz_rdn = (size_t)BATCH * NPTS * sizeof(double);
    const size_t sz_ss  = sz_rdn;

    unsigned short* pk = (unsigned short*)(ws);
    float*  x_rm   = (float*) (ws + sz_pk);
    double* rdnd   = (double*)(ws + sz_pk + sz_xrm);
    double* ssd    = (double*)(ws + sz_pk + sz_xrm + sz_rdn);
    unsigned* cand_p = (unsigned*)(ws + sz_pk + sz_xrm + sz_rdn + sz_ss);                // 25.17 MB

    knn_normalize<<<BATCH * (NPTS / NT), 256, 0, stream>>>(x, pk, x_rm, rdnd, ssd);
    knn_phase1  <<<BATCH * 64 * CSPLIT, 256, 0, stream>>>(pk, cand_p);
    knn_phase2  <<<BATCH * (NPTS / P2ROWS), 256, 0, stream>>>(x_rm, rdnd, ssd, cand_p, out);
}

// Round 8
// 190.513 us; speedup vs baseline: 8.4429x; 1.2847x over previous
//
#include <hip/hip_runtime.h>
#include <math.h>

#define BATCH 2
#define CH    192
#define NPTS  8192
#define KNN   9

#define NT     64      // rows per normalize block
#define TLIST  5       // per-bucket candidate list depth
#define NTILE  512     // 16-wide row/col tiles per batch
#define KSTEP  6       // 192 / 32
#define CSPLIT 8       // column splits (phase 1)
#define CT     2       // col tiles staged per iteration
#define NITER  ((NTILE / CSPLIT) / CT)   // 32
#define NCANDP 640     // packed candidates per row (8 cs * 16 bins * 5)
#define P2ROWS 4       // phase-2 rows per block (1 per wave)

typedef __attribute__((ext_vector_type(8))) short  bf16x8;
typedef __attribute__((ext_vector_type(8))) unsigned short u16x8;
typedef __attribute__((ext_vector_type(4))) float  f32x4;

static __device__ __forceinline__ unsigned short f2bf(float f) {
    unsigned u = __float_as_uint(f);
    u += 0x7fffu + ((u >> 16) & 1u);          // round-to-nearest-even
    return (unsigned short)(u >> 16);
}
static __device__ __forceinline__ bf16x8 negbf(bf16x8 v) {
    bf16x8 r;
    #pragma unroll
    for (int e = 0; e < 8; ++e) r[e] = (short)(v[e] ^ (short)0x8000);
    return r;
}
static __device__ __forceinline__ unsigned umax2(unsigned a, unsigned b) {
    return a > b ? a : b;
}

// ---------------------------------------------------------------------------
// Kernel A: norms + layouts. pk is HI-ONLY bf16 MFMA-frag layout:
//  pk [B][tile(512)][ks(6)][lane(64)*8] bf16
//     element: row = tile*16 + (lane&15), k = ks*32 + (lane>>4)*8 + e
//  x_rm [B][N][C] f32 raw; rdnd/ssd f64 per point.
// ---------------------------------------------------------------------------
__global__ __launch_bounds__(256) void knn_normalize(
    const float* __restrict__ x,
    unsigned short* __restrict__ pk, float* __restrict__ x_rm,
    double* __restrict__ rdnd, double* __restrict__ ssd)
{
    __shared__ float  tile[CH][NT + 1];
    __shared__ double rdn_sh[NT];

    const int b   = blockIdx.x >> 7;
    const int rb  = blockIdx.x & 127;
    const int n0  = rb << 6;
    const int tid = threadIdx.x;
    const float* xb = x + (size_t)b * CH * NPTS;

    #pragma unroll
    for (int i = 0; i < (CH * NT) / 256; ++i) {
        int flat = tid + i * 256;
        int c = flat >> 6, j = flat & 63;
        tile[c][j] = xb[(size_t)c * NPTS + n0 + j];
    }
    __syncthreads();

    if (tid < NT) {
        double ss = 0.0;
        #pragma unroll 8
        for (int c = 0; c < CH; ++c) {
            double v = (double)tile[c][tid];
            ss = fma(v, v, ss);
        }
        double dn = sqrt(ss);
        if (dn < 1e-12) dn = 1e-12;
        double rdn = 1.0 / dn;
        rdn_sh[tid] = rdn;
        rdnd[b * NPTS + n0 + tid] = rdn;
        ssd [b * NPTS + n0 + tid] = ss;
    }
    __syncthreads();

    // packed MFMA-frag bf16 hi (4 row-tiles * 6 ksteps = 24 frags/block)
    #pragma unroll
    for (int i = 0; i < 6; ++i) {
        int pid  = tid + i * 256;
        int frag = pid >> 6;
        int lane = pid & 63;
        int tl   = frag / KSTEP;
        int ks   = frag - tl * KSTEP;
        int rl   = (tl << 4) + (lane & 15);
        int kb   = (ks << 5) + ((lane >> 4) << 3);
        double rdn = rdn_sh[rl];
        u16x8 hv;
        #pragma unroll
        for (int e = 0; e < 8; ++e) {
            float v = (float)((double)tile[kb + e][rl] * rdn);
            hv[e] = f2bf(v);
        }
        size_t base = ((size_t)((b * NTILE + (rb << 2) + tl) * KSTEP + ks)) * 512
                      + ((size_t)lane << 3);
        *(u16x8*)(pk + base) = hv;
    }

    #pragma unroll
    for (int i = 0; i < (CH * NT) / 256; ++i) {
        int flat = tid + i * 256;
        int j = flat / CH, c = flat - j * CH;
        x_rm[(size_t)(b * NPTS + n0 + j) * CH + c] = tile[c][j];
    }
}

// ---------------------------------------------------------------------------
// Phase 1 v5: hi-only bf16 MFMA (1 MFMA per kstep). Grid 1024 (4 blocks/CU),
// negated-A bias-4 keys (acc = 4 - inner_hh, positive -> uint order = float
// order). Depth-5 lists, replace-equal-to-max. 24 KB LDS double-buffer.
// Bucket = (cs, col&15): 128 buckets x 5 = 640 candidates/row.
// ---------------------------------------------------------------------------
__global__ __launch_bounds__(256, 4) void knn_phase1(
    const unsigned short* __restrict__ pk,
    unsigned* __restrict__ cand_p)
{
    __shared__ unsigned short ldsB[2][CT * KSTEP * 512];   // 2 x 12288 B

    const int bid  = blockIdx.x;          // 1024
    const int b    = bid >> 9;
    const int r9   = bid & 511;
    const int rb   = r9 >> 3;             // row block (128 rows), 0..63
    const int cs   = r9 & 7;              // column split, 0..7
    const int tid  = threadIdx.x;
    const int wave = tid >> 6;
    const int lane = tid & 63;
    const unsigned short* pkb = pk + (size_t)b * (NTILE * KSTEP * 512);
    const int ct0 = cs * (NTILE / CSPLIT);       // 64 tiles per split

    // A fragments: 2 row tiles per wave, NEGATED (for acc = 4 - inner)
    bf16x8 a_hi[2][KSTEP];
    #pragma unroll
    for (int ri = 0; ri < 2; ++ri) {
        const int rt = rb * 8 + wave * 2 + ri;
        #pragma unroll
        for (int ks = 0; ks < KSTEP; ++ks) {
            const unsigned short* p = pkb + ((size_t)(rt * KSTEP + ks)) * 512 + (lane << 3);
            a_hi[ri][ks] = negbf(*(const bf16x8*)p);
        }
    }

    // packed lists; sentinels above all real keys (real < 0x40C00000)
    unsigned lst[8][TLIST];
    unsigned wmax[8];
    #pragma unroll
    for (int s = 0; s < 8; ++s) {
        #pragma unroll
        for (int t = 0; t < TLIST; ++t) lst[s][t] = 0xFFFFFF00u | t;
        wmax[s] = 0xFFFFFF00u | (TLIST - 1);
    }

    // prologue stage of buffer 0 (12 KB = 3 x 256 x 16B)
    {
        const char* g = (const char*)(pkb + (size_t)ct0 * (KSTEP * 512));
        #pragma unroll
        for (int k = 0; k < 3; ++k) {
            int off = (k * 256 + tid) * 16;
            __builtin_amdgcn_global_load_lds(
                (const __attribute__((address_space(1))) unsigned int*)(g + off),
                (__attribute__((address_space(3))) unsigned int*)((char*)&ldsB[0][0] + off),
                16, 0, 0);
        }
    }
    __syncthreads();

    for (int it = 0; it < NITER; ++it) {
        const int cur = it & 1;
        if (it + 1 < NITER) {
            const char* g = (const char*)(pkb + (size_t)(ct0 + (it + 1) * CT) * (KSTEP * 512));
            #pragma unroll
            for (int k = 0; k < 3; ++k) {
                int off = (k * 256 + tid) * 16;
                __builtin_amdgcn_global_load_lds(
                    (const __attribute__((address_space(1))) unsigned int*)(g + off),
                    (__attribute__((address_space(3))) unsigned int*)((char*)&ldsB[cur ^ 1][0] + off),
                    16, 0, 0);
            }
        }

        f32x4 acc[2][CT];
        #pragma unroll
        for (int ri = 0; ri < 2; ++ri)
            #pragma unroll
            for (int j = 0; j < CT; ++j) acc[ri][j] = (f32x4){4.f, 4.f, 4.f, 4.f};

        #pragma unroll
        for (int ks = 0; ks < KSTEP; ++ks) {
            bf16x8 bh[CT];
            #pragma unroll
            for (int j = 0; j < CT; ++j)
                bh[j] = *(const bf16x8*)&ldsB[cur][(j * KSTEP + ks) * 512 + (lane << 3)];
            #pragma unroll
            for (int ri = 0; ri < 2; ++ri)
                #pragma unroll
                for (int j = 0; j < CT; ++j)
                    acc[ri][j] = __builtin_amdgcn_mfma_f32_16x16x32_bf16(a_hi[ri][ks], bh[j], acc[ri][j], 0, 0, 0);
        }

        // selection: key = 4 - inner (positive) -> p = (bits & ~0x7F) | tile
        #pragma unroll
        for (int ri = 0; ri < 2; ++ri)
            #pragma unroll
            for (int j = 0; j < CT; ++j) {
                const unsigned ctl = (unsigned)(it * CT + j);   // 0..63
                #pragma unroll
                for (int s = 0; s < 4; ++s) {
                    const int sl = ri * 4 + s;
                    unsigned p = (__float_as_uint(acc[ri][j][s]) & 0xFFFFFF80u) | ctl;
                    const unsigned wm = wmax[sl];
                    if (p < wm) {
                        #pragma unroll
                        for (int t = 0; t < TLIST; ++t)
                            lst[sl][t] = (lst[sl][t] == wm) ? p : lst[sl][t];
                        unsigned m0 = umax2(umax2(lst[sl][0], lst[sl][1]), lst[sl][2]);
                        wmax[sl] = umax2(umax2(m0, lst[sl][3]), lst[sl][4]);
                    }
                }
            }
        __syncthreads();
    }

    // write candidates: [B*N][640], slot = cs*80 + bin*5 + t
    const int bin = lane & 15;
    #pragma unroll
    for (int ri = 0; ri < 2; ++ri) {
        const int rt = rb * 8 + wave * 2 + ri;
        #pragma unroll
        for (int s = 0; s < 4; ++s) {
            int row = (rt << 4) + ((lane >> 4) << 2) + s;
            size_t base = (size_t)(b * NPTS + row) * NCANDP + cs * 80 + bin * 5;
            #pragma unroll
            for (int t = 0; t < TLIST; ++t)
                cand_p[base + t] = lst[ri * 4 + s][t];
        }
    }
}

// ---------------------------------------------------------------------------
// Phase 2: 1 row per wave, 4 rows/block, 4096 blocks.
//  (a) per-lane 10 packed cands (2 buckets of 5), insertion-sort, 16-round
//      wave-min extraction
//  (b) f64 re-rank: lane=(cand,quarter), float4 gathers, 2-shfl reduce
//  (c) lane-0 serial 9-of-16 by (f64 key, idx)
// ---------------------------------------------------------------------------
__global__ __launch_bounds__(256) void knn_phase2(
    const float* __restrict__ x_rm,
    const double* __restrict__ rdnd, const double* __restrict__ ssd,
    const unsigned* __restrict__ cand_p,
    int* __restrict__ out)
{
    __shared__ double xc[P2ROWS][CH];     // 6144 B
    __shared__ int    sel[P2ROWS][16];
    __shared__ double dks[P2ROWS][16];

    const int bi   = blockIdx.x;          // 4096
    const int b    = bi >> 11;
    const int r0   = (bi & 2047) << 2;
    const int tid  = threadIdx.x;
    const int wave = tid >> 6;
    const int lane = tid & 63;
    const int bN   = b * NPTS;

    for (int i = tid; i < P2ROWS * CH; i += 256) {
        int r = i / CH, c = i - r * CH;
        xc[r][c] = (double)x_rm[(size_t)(bN + r0 + r) * CH + c] * rdnd[bN + r0 + r];
    }
    __syncthreads();

    const int row = r0 + wave;

    // (a) lane's 10 slots: cs = lane>>3; bins (lane&7)*2 + u/5
    unsigned long long qq[10];
    {
        const unsigned* cp = cand_p + (size_t)(bN + row) * NCANDP + lane * 10;
        const int csq = lane >> 3;
        const int bin0 = (lane & 7) << 1;
        #pragma unroll
        for (int u = 0; u < 10; ++u) {
            unsigned pkv = cp[u];
            int bin = bin0 + (u >= TLIST);
            int col = ((csq << 6) + (int)(pkv & 0x7Fu)) * 16 + bin;
            qq[u] = ((unsigned long long)pkv << 32) | (unsigned)col;
        }
        // insertion sort 10 ascending (static indices)
        #pragma unroll
        for (int i = 1; i < 10; ++i)
            #pragma unroll
            for (int jj = i; jj > 0; --jj)
                if (qq[jj] < qq[jj - 1]) {
                    unsigned long long t = qq[jj - 1];
                    qq[jj - 1] = qq[jj]; qq[jj] = t;
                }
    }

    // 16 extraction rounds of wave-wide u64 min; lane r captures round r
    unsigned long long my_sel = 0;
    #pragma unroll
    for (int round = 0; round < 16; ++round) {
        unsigned long long m = qq[0];
        #pragma unroll
        for (int off = 1; off < 64; off <<= 1) {
            unsigned long long o = __shfl_xor(m, off, 64);
            m = (o < m) ? o : m;
        }
        if (qq[0] == m) {                 // exactly one lane (u64 unique via col)
            #pragma unroll
            for (int u = 0; u < 9; ++u) qq[u] = qq[u + 1];
            qq[9] = 0xFFFFFFFFFFFFFFFFull;
        }
        if (lane == round) my_sel = m;
    }
    if (lane < 16) sel[wave][lane] = (int)((unsigned)my_sel & 0x3FFFu);
    __builtin_amdgcn_wave_barrier();

    // (b) exact f64 keys: lane = (cand c, quarter qd)
    {
        const int c = lane & 15, qd = lane >> 4;
        const int m = sel[wave][c];
        const double rdm = rdnd[bN + m];
        const float* xr = x_rm + (size_t)(bN + m) * CH + qd * 48;
        const double* xcp = &xc[wave][qd * 48];
        double s0 = 0.0, s1 = 0.0, s2 = 0.0, s3 = 0.0;
        #pragma unroll
        for (int j = 0; j < 12; ++j) {
            float4 v = *(const float4*)(xr + (j << 2));
            s0 = fma((double)v.x * rdm, xcp[(j << 2) + 0], s0);
            s1 = fma((double)v.y * rdm, xcp[(j << 2) + 1], s1);
            s2 = fma((double)v.z * rdm, xcp[(j << 2) + 2], s2);
            s3 = fma((double)v.w * rdm, xcp[(j << 2) + 3], s3);
        }
        double dot = (s0 + s1) + (s2 + s3);
        dot += __shfl_xor(dot, 16, 64);
        dot += __shfl_xor(dot, 32, 64);
        if (qd == 0) dks[wave][c] = fma(-2.0, dot, ssd[bN + m] * rdm * rdm);
    }
    __builtin_amdgcn_wave_barrier();

    // (c) 9 smallest of 16 by (key, idx) — serial on lane 0 of each wave
    if (lane == 0) {
        const int n = row;
        unsigned used = 0;
        for (int k = 0; k < KNN; ++k) {
            double bd = INFINITY; int bm = 0x7fffffff; int bp = 0;
            #pragma unroll
            for (int s = 0; s < 16; ++s) {
                if (!((used >> s) & 1u)) {
                    double d = dks[wave][s]; int m = sel[wave][s];
                    if (d < bd || (d == bd && m < bm)) { bd = d; bm = m; bp = s; }
                }
            }
            used |= (1u << bp);
            out[(size_t)(bN + n) * KNN + k] = bm;
            out[(size_t)BATCH * NPTS * KNN + (size_t)(bN + n) * KNN + k] = n;
        }
    }
}

// ---------------------------------------------------------------------------
extern "C" void kernel_launch(void* const* d_in, const int* in_sizes, int n_in,
                              void* d_out, int out_size, void* d_ws, size_t ws_size,
                              hipStream_t stream)
{
    const float* x = (const float*)d_in[0];
    int* out = (int*)d_out;

    char* ws = (char*)d_ws;
    const size_t sz_pk  = (size_t)BATCH * NTILE * KSTEP * 512 * sizeof(unsigned short); // 6.29 MB
    const size_t sz_xrm = (size_t)BATCH * NPTS * CH * sizeof(float);                    // 12.58 MB
    const size_t sz_rdn = (size_t)BATCH * NPTS * sizeof(double);
    const size_t sz_ss  = sz_rdn;

    unsigned short* pk = (unsigned short*)(ws);
    float*  x_rm   = (float*) (ws + sz_pk);
    double* rdnd   = (double*)(ws + sz_pk + sz_xrm);
    double* ssd    = (double*)(ws + sz_pk + sz_xrm + sz_rdn);
    unsigned* cand_p = (unsigned*)(ws + sz_pk + sz_xrm + sz_rdn + sz_ss);               // 41.9 MB

    knn_normalize<<<BATCH * (NPTS / NT), 256, 0, stream>>>(x, pk, x_rm, rdnd, ssd);
    knn_phase1  <<<BATCH * 64 * CSPLIT, 256, 0, stream>>>(pk, cand_p);
    knn_phase2  <<<BATCH * (NPTS / P2ROWS), 256, 0, stream>>>(x_rm, rdnd, ssd, cand_p, out);
}

// Round 9
// 183.929 us; speedup vs baseline: 8.7451x; 1.0358x over previous
//
#include <hip/hip_runtime.h>
#include <math.h>

#define BATCH 2
#define CH    192
#define NPTS  8192
#define KNN   9

#define NT     64      // rows per normalize block
#define TLIST  5       // per-bucket candidate list depth
#define NTILE  512     // 16-wide row/col tiles per batch
#define KSTEP  6       // 192 / 32
#define CSPLIT 8       // column splits (phase 1)
#define CT     2       // col tiles staged per iteration
#define NITER  ((NTILE / CSPLIT) / CT)   // 32
#define NCANDP 640     // packed candidates per row (8 cs * 16 bins * 5)
#define P2ROWS 4       // phase-2 rows per block (1 per wave)

typedef __attribute__((ext_vector_type(8))) short  bf16x8;
typedef __attribute__((ext_vector_type(8))) unsigned short u16x8;
typedef __attribute__((ext_vector_type(4))) float  f32x4;

static __device__ __forceinline__ unsigned short f2bf(float f) {
    unsigned u = __float_as_uint(f);
    u += 0x7fffu + ((u >> 16) & 1u);          // round-to-nearest-even
    return (unsigned short)(u >> 16);
}
static __device__ __forceinline__ bf16x8 negbf(bf16x8 v) {
    bf16x8 r;
    #pragma unroll
    for (int e = 0; e < 8; ++e) r[e] = (short)(v[e] ^ (short)0x8000);
    return r;
}
static __device__ __forceinline__ unsigned umax2(unsigned a, unsigned b) {
    return a > b ? a : b;
}

// ---------------------------------------------------------------------------
// Kernel A: norms + layouts. pk is HI-ONLY bf16 MFMA-frag layout:
//  pk [B][tile(512)][ks(6)][lane(64)*8] bf16
//     element: row = tile*16 + (lane&15), k = ks*32 + (lane>>4)*8 + e
//  x_rm [B][N][C] f32 raw; rdnd/ssd f64 per point.
// Norm reduction: 4 threads per point (48 dims each) + f64 shfl reduce.
// ---------------------------------------------------------------------------
__global__ __launch_bounds__(256) void knn_normalize(
    const float* __restrict__ x,
    unsigned short* __restrict__ pk, float* __restrict__ x_rm,
    double* __restrict__ rdnd, double* __restrict__ ssd)
{
    __shared__ float  tile[CH][NT + 1];
    __shared__ double rdn_sh[NT];

    const int b   = blockIdx.x >> 7;
    const int rb  = blockIdx.x & 127;
    const int n0  = rb << 6;
    const int tid = threadIdx.x;
    const float* xb = x + (size_t)b * CH * NPTS;

    #pragma unroll
    for (int i = 0; i < (CH * NT) / 256; ++i) {
        int flat = tid + i * 256;
        int c = flat >> 6, j = flat & 63;
        tile[c][j] = xb[(size_t)c * NPTS + n0 + j];
    }
    __syncthreads();

    // 4 threads per point: quarter q covers dims q*48..q*48+47
    {
        const int j = tid >> 2, q = tid & 3;
        double ss = 0.0;
        #pragma unroll 8
        for (int c = 0; c < 48; ++c) {
            double v = (double)tile[q * 48 + c][j];
            ss = fma(v, v, ss);
        }
        ss += __shfl_xor(ss, 1, 64);
        ss += __shfl_xor(ss, 2, 64);
        if (q == 0) {
            double dn = sqrt(ss);
            if (dn < 1e-12) dn = 1e-12;
            double rdn = 1.0 / dn;
            rdn_sh[j] = rdn;
            rdnd[b * NPTS + n0 + j] = rdn;
            ssd [b * NPTS + n0 + j] = ss;
        }
    }
    __syncthreads();

    // packed MFMA-frag bf16 hi (4 row-tiles * 6 ksteps = 24 frags/block)
    #pragma unroll
    for (int i = 0; i < 6; ++i) {
        int pid  = tid + i * 256;
        int frag = pid >> 6;
        int lane = pid & 63;
        int tl   = frag / KSTEP;
        int ks   = frag - tl * KSTEP;
        int rl   = (tl << 4) + (lane & 15);
        int kb   = (ks << 5) + ((lane >> 4) << 3);
        double rdn = rdn_sh[rl];
        u16x8 hv;
        #pragma unroll
        for (int e = 0; e < 8; ++e) {
            float v = (float)((double)tile[kb + e][rl] * rdn);
            hv[e] = f2bf(v);
        }
        size_t base = ((size_t)((b * NTILE + (rb << 2) + tl) * KSTEP + ks)) * 512
                      + ((size_t)lane << 3);
        *(u16x8*)(pk + base) = hv;
    }

    #pragma unroll
    for (int i = 0; i < (CH * NT) / 256; ++i) {
        int flat = tid + i * 256;
        int j = flat / CH, c = flat - j * CH;
        x_rm[(size_t)(b * NPTS + n0 + j) * CH + c] = tile[c][j];
    }
}

// ---------------------------------------------------------------------------
// Phase 1 v6: as R8 (hi-only bf16 MFMA, bias-4 keys, depth-5 lists) but
// pinned to exactly 4 waves/EU so the allocator keeps a_hi + lst in arch
// VGPRs (R8's VGPR=64 put lists in AGPRs -> accvgpr ping-pong ~2x VALU).
// bh loaded one col-tile at a time to stay under the 128-reg cap.
// ---------------------------------------------------------------------------
__global__ __attribute__((amdgpu_flat_work_group_size(256, 256),
                          amdgpu_waves_per_eu(4, 4)))
void knn_phase1(
    const unsigned short* __restrict__ pk,
    unsigned* __restrict__ cand_p)
{
    __shared__ unsigned short ldsB[2][CT * KSTEP * 512];   // 2 x 12288 B

    const int bid  = blockIdx.x;          // 1024
    const int b    = bid >> 9;
    const int r9   = bid & 511;
    const int rb   = r9 >> 3;             // row block (128 rows), 0..63
    const int cs   = r9 & 7;              // column split, 0..7
    const int tid  = threadIdx.x;
    const int wave = tid >> 6;
    const int lane = tid & 63;
    const unsigned short* pkb = pk + (size_t)b * (NTILE * KSTEP * 512);
    const int ct0 = cs * (NTILE / CSPLIT);       // 64 tiles per split

    // A fragments: 2 row tiles per wave, NEGATED (for acc = 4 - inner)
    bf16x8 a_hi[2][KSTEP];
    #pragma unroll
    for (int ri = 0; ri < 2; ++ri) {
        const int rt = rb * 8 + wave * 2 + ri;
        #pragma unroll
        for (int ks = 0; ks < KSTEP; ++ks) {
            const unsigned short* p = pkb + ((size_t)(rt * KSTEP + ks)) * 512 + (lane << 3);
            a_hi[ri][ks] = negbf(*(const bf16x8*)p);
        }
    }

    // packed lists; sentinels above all real keys (real < 0x40C00000)
    unsigned lst[8][TLIST];
    unsigned wmax[8];
    #pragma unroll
    for (int s = 0; s < 8; ++s) {
        #pragma unroll
        for (int t = 0; t < TLIST; ++t) lst[s][t] = 0xFFFFFF00u | t;
        wmax[s] = 0xFFFFFF00u | (TLIST - 1);
    }

    // prologue stage of buffer 0 (12 KB = 3 x 256 x 16B)
    {
        const char* g = (const char*)(pkb + (size_t)ct0 * (KSTEP * 512));
        #pragma unroll
        for (int k = 0; k < 3; ++k) {
            int off = (k * 256 + tid) * 16;
            __builtin_amdgcn_global_load_lds(
                (const __attribute__((address_space(1))) unsigned int*)(g + off),
                (__attribute__((address_space(3))) unsigned int*)((char*)&ldsB[0][0] + off),
                16, 0, 0);
        }
    }
    __syncthreads();

    for (int it = 0; it < NITER; ++it) {
        const int cur = it & 1;
        if (it + 1 < NITER) {
            const char* g = (const char*)(pkb + (size_t)(ct0 + (it + 1) * CT) * (KSTEP * 512));
            #pragma unroll
            for (int k = 0; k < 3; ++k) {
                int off = (k * 256 + tid) * 16;
                __builtin_amdgcn_global_load_lds(
                    (const __attribute__((address_space(1))) unsigned int*)(g + off),
                    (__attribute__((address_space(3))) unsigned int*)((char*)&ldsB[cur ^ 1][0] + off),
                    16, 0, 0);
            }
        }

        f32x4 acc[2][CT];
        #pragma unroll
        for (int ri = 0; ri < 2; ++ri)
            #pragma unroll
            for (int j = 0; j < CT; ++j) acc[ri][j] = (f32x4){4.f, 4.f, 4.f, 4.f};

        #pragma unroll
        for (int ks = 0; ks < KSTEP; ++ks) {
            #pragma unroll
            for (int j = 0; j < CT; ++j) {
                bf16x8 bh = *(const bf16x8*)&ldsB[cur][(j * KSTEP + ks) * 512 + (lane << 3)];
                acc[0][j] = __builtin_amdgcn_mfma_f32_16x16x32_bf16(a_hi[0][ks], bh, acc[0][j], 0, 0, 0);
                acc[1][j] = __builtin_amdgcn_mfma_f32_16x16x32_bf16(a_hi[1][ks], bh, acc[1][j], 0, 0, 0);
            }
        }

        // selection: key = 4 - inner (positive) -> p = (bits & ~0x7F) | tile
        #pragma unroll
        for (int ri = 0; ri < 2; ++ri)
            #pragma unroll
            for (int j = 0; j < CT; ++j) {
                const unsigned ctl = (unsigned)(it * CT + j);   // 0..63
                #pragma unroll
                for (int s = 0; s < 4; ++s) {
                    const int sl = ri * 4 + s;
                    unsigned p = (__float_as_uint(acc[ri][j][s]) & 0xFFFFFF80u) | ctl;
                    const unsigned wm = wmax[sl];
                    if (p < wm) {
                        #pragma unroll
                        for (int t = 0; t < TLIST; ++t)
                            lst[sl][t] = (lst[sl][t] == wm) ? p : lst[sl][t];
                        unsigned m0 = umax2(umax2(lst[sl][0], lst[sl][1]), lst[sl][2]);
                        wmax[sl] = umax2(umax2(m0, lst[sl][3]), lst[sl][4]);
                    }
                }
            }
        __syncthreads();
    }

    // write candidates: [B*N][640], slot = cs*80 + bin*5 + t
    const int bin = lane & 15;
    #pragma unroll
    for (int ri = 0; ri < 2; ++ri) {
        const int rt = rb * 8 + wave * 2 + ri;
        #pragma unroll
        for (int s = 0; s < 4; ++s) {
            int row = (rt << 4) + ((lane >> 4) << 2) + s;
            size_t base = (size_t)(b * NPTS + row) * NCANDP + cs * 80 + bin * 5;
            #pragma unroll
            for (int t = 0; t < TLIST; ++t)
                cand_p[base + t] = lst[ri * 4 + s][t];
        }
    }
}

// ---------------------------------------------------------------------------
// Phase 2 (unchanged from R8 — passing): 1 row per wave, 4 rows/block.
//  (a) per-lane 10 packed cands (2 buckets of 5), insertion-sort, 16-round
//      wave-min extraction
//  (b) f64 re-rank: lane=(cand,quarter), float4 gathers, 2-shfl reduce
//  (c) lane-0 serial 9-of-16 by (f64 key, idx)
// ---------------------------------------------------------------------------
__global__ __launch_bounds__(256) void knn_phase2(
    const float* __restrict__ x_rm,
    const double* __restrict__ rdnd, const double* __restrict__ ssd,
    const unsigned* __restrict__ cand_p,
    int* __restrict__ out)
{
    __shared__ double xc[P2ROWS][CH];     // 6144 B
    __shared__ int    sel[P2ROWS][16];
    __shared__ double dks[P2ROWS][16];

    const int bi   = blockIdx.x;          // 4096
    const int b    = bi >> 11;
    const int r0   = (bi & 2047) << 2;
    const int tid  = threadIdx.x;
    const int wave = tid >> 6;
    const int lane = tid & 63;
    const int bN   = b * NPTS;

    for (int i = tid; i < P2ROWS * CH; i += 256) {
        int r = i / CH, c = i - r * CH;
        xc[r][c] = (double)x_rm[(size_t)(bN + r0 + r) * CH + c] * rdnd[bN + r0 + r];
    }
    __syncthreads();

    const int row = r0 + wave;

    // (a) lane's 10 slots: cs = lane>>3; bins (lane&7)*2 + u/5
    unsigned long long qq[10];
    {
        const unsigned* cp = cand_p + (size_t)(bN + row) * NCANDP + lane * 10;
        const int csq = lane >> 3;
        const int bin0 = (lane & 7) << 1;
        #pragma unroll
        for (int u = 0; u < 10; ++u) {
            unsigned pkv = cp[u];
            int bin = bin0 + (u >= TLIST);
            int col = ((csq << 6) + (int)(pkv & 0x7Fu)) * 16 + bin;
            qq[u] = ((unsigned long long)pkv << 32) | (unsigned)col;
        }
        // insertion sort 10 ascending (static indices)
        #pragma unroll
        for (int i = 1; i < 10; ++i)
            #pragma unroll
            for (int jj = i; jj > 0; --jj)
                if (qq[jj] < qq[jj - 1]) {
                    unsigned long long t = qq[jj - 1];
                    qq[jj - 1] = qq[jj]; qq[jj] = t;
                }
    }

    // 16 extraction rounds of wave-wide u64 min; lane r captures round r
    unsigned long long my_sel = 0;
    #pragma unroll
    for (int round = 0; round < 16; ++round) {
        unsigned long long m = qq[0];
        #pragma unroll
        for (int off = 1; off < 64; off <<= 1) {
            unsigned long long o = __shfl_xor(m, off, 64);
            m = (o < m) ? o : m;
        }
        if (qq[0] == m) {                 // exactly one lane (u64 unique via col)
            #pragma unroll
            for (int u = 0; u < 9; ++u) qq[u] = qq[u + 1];
            qq[9] = 0xFFFFFFFFFFFFFFFFull;
        }
        if (lane == round) my_sel = m;
    }
    if (lane < 16) sel[wave][lane] = (int)((unsigned)my_sel & 0x3FFFu);
    __builtin_amdgcn_wave_barrier();

    // (b) exact f64 keys: lane = (cand c, quarter qd)
    {
        const int c = lane & 15, qd = lane >> 4;
        const int m = sel[wave][c];
        const double rdm = rdnd[bN + m];
        const float* xr = x_rm + (size_t)(bN + m) * CH + qd * 48;
        const double* xcp = &xc[wave][qd * 48];
        double s0 = 0.0, s1 = 0.0, s2 = 0.0, s3 = 0.0;
        #pragma unroll
        for (int j = 0; j < 12; ++j) {
            float4 v = *(const float4*)(xr + (j << 2));
            s0 = fma((double)v.x * rdm, xcp[(j << 2) + 0], s0);
            s1 = fma((double)v.y * rdm, xcp[(j << 2) + 1], s1);
            s2 = fma((double)v.z * rdm, xcp[(j << 2) + 2], s2);
            s3 = fma((double)v.w * rdm, xcp[(j << 2) + 3], s3);
        }
        double dot = (s0 + s1) + (s2 + s3);
        dot += __shfl_xor(dot, 16, 64);
        dot += __shfl_xor(dot, 32, 64);
        if (qd == 0) dks[wave][c] = fma(-2.0, dot, ssd[bN + m] * rdm * rdm);
    }
    __builtin_amdgcn_wave_barrier();

    // (c) 9 smallest of 16 by (key, idx) — serial on lane 0 of each wave
    if (lane == 0) {
        const int n = row;
        unsigned used = 0;
        for (int k = 0; k < KNN; ++k) {
            double bd = INFINITY; int bm = 0x7fffffff; int bp = 0;
            #pragma unroll
            for (int s = 0; s < 16; ++s) {
                if (!((used >> s) & 1u)) {
                    double d = dks[wave][s]; int m = sel[wave][s];
                    if (d < bd || (d == bd && m < bm)) { bd = d; bm = m; bp = s; }
                }
            }
            used |= (1u << bp);
            out[(size_t)(bN + n) * KNN + k] = bm;
            out[(size_t)BATCH * NPTS * KNN + (size_t)(bN + n) * KNN + k] = n;
        }
    }
}

// ---------------------------------------------------------------------------
extern "C" void kernel_launch(void* const* d_in, const int* in_sizes, int n_in,
                              void* d_out, int out_size, void* d_ws, size_t ws_size,
                              hipStream_t stream)
{
    const float* x = (const float*)d_in[0];
    int* out = (int*)d_out;

    char* ws = (char*)d_ws;
    const size_t sz_pk  = (size_t)BATCH * NTILE * KSTEP * 512 * sizeof(unsigned short); // 6.29 MB
    const size_t sz_xrm = (size_t)BATCH * NPTS * CH * sizeof(float);                    // 12.58 MB
    const size_t sz_rdn = (size_t)BATCH * NPTS * sizeof(double);
    const size_t sz_ss  = sz_rdn;

    unsigned short* pk = (unsigned short*)(ws);
    float*  x_rm   = (float*) (ws + sz_pk);
    double* rdnd   = (double*)(ws + sz_pk + sz_xrm);
    double* ssd    = (double*)(ws + sz_pk + sz_xrm + sz_rdn);
    unsigned* cand_p = (unsigned*)(ws + sz_pk + sz_xrm + sz_rdn + sz_ss);               // 41.9 MB

    knn_normalize<<<BATCH * (NPTS / NT), 256, 0, stream>>>(x, pk, x_rm, rdnd, ssd);
    knn_phase1  <<<BATCH * 64 * CSPLIT, 256, 0, stream>>>(pk, cand_p);
    knn_phase2  <<<BATCH * (NPTS / P2ROWS), 256, 0, stream>>>(x_rm, rdnd, ssd, cand_p, out);
}